// Round 11
// baseline (240.866 us; speedup 1.0000x reference)
//
#include <hip/hip_runtime.h>
#include <hip/hip_bf16.h>
#include <math.h>

// Problem constants
#define BB   32
#define HH   40
#define WW   256
#define NF   40          // FREQ
#define H1N  36
#define W1N  252
#define KCNN 580608      // 64*36*252
#define KT   256         // k2: k per LDS tile
#define NBLK2 1134       // k2 blocks; 2 tiles each (2268 tiles * 256 == KCNN exactly)

typedef __attribute__((ext_vector_type(8))) short bf16x8;   // 8 bf16 = 4 VGPRs
typedef __attribute__((ext_vector_type(4))) float f32x4;    // MFMA C/D

static __device__ __forceinline__ unsigned short f2bf(float v) {
    __hip_bfloat16 h = __float2bfloat16(v);
    return *(unsigned short*)&h;
}

// ---------------- K0: w1 repack f32->bf16; sin/cos table; zero gacc8/mean ----------
__global__ void k0_prep(const float* __restrict__ w1, unsigned short* __restrict__ w1c,
                        float* __restrict__ gacc8, float* __restrict__ sintab,
                        float* __restrict__ costab, float* __restrict__ out) {
    int o = blockIdx.x * 256 + threadIdx.x;   // 72*256 = 18432 = 9*64*32
    int c0  = o & 31;
    int c1  = (o >> 5) & 63;
    int tap = o >> 11;                        // 0..8
    w1c[o] = f2bf(w1[(c1 * 32 + c0) * 9 + tap]);
    if (o < 10240) {                          // 40 f x 256 w phase table + gacc8 zero
        int f = o >> 8, w = o & 255;
        float ph = 6.283185307179586f * (float)(f + 1) * (1.0f / 255.0f) * (float)w;
        sintab[o] = sinf(ph);
        costab[o] = cosf(ph);
        gacc8[o] = 0.0f;                      // 8 replicas x 1280 = 10240 floats
    }
    if (o == 0) out[51200] = 0.0f;
}

// ---------------- K1: fused conv0(relu) + conv1(relu) via bf16 MFMA -> x (bf16) --------
// (byte-identical to round-9 measured version)
__global__ __launch_bounds__(256) void k1_conv(
        const float* __restrict__ inp, const float* __restrict__ w0,
        const float* __restrict__ b0, const unsigned short* __restrict__ w1c,
        const float* __restrict__ b1, unsigned short* __restrict__ xbf) {
    __shared__ __align__(16) char smem[33856];
    float* ins = (float*)smem;                              // 544*4  = 2176 B
    unsigned short* y0T = (unsigned short*)(smem + 2176);   // 396*40*2 = 31680 B
    unsigned short* stg = (unsigned short*)smem;            // epilogue reuse: 32768 B

    const int jt = blockIdx.x;        // j0 = 64*jt
    const int it = blockIdx.y;        // i0 = 4*it
    const int b  = blockIdx.z;
    const int i0 = it * 4;
    const int j0 = jt * 64;
    const int tid = threadIdx.x;

    // ---- stage input rows i0..i0+7, cols j0..j0+67 (float4; jt==3 edge zeroed) ----
    if (tid < 136) {
        int r  = tid / 17, c4 = tid - r * 17;
        float4 v = {0.f, 0.f, 0.f, 0.f};
        if (jt < 3 || c4 < 16)        // cols j0+64..67 exceed WW only at jt==3
            v = *(const float4*)(inp + (b * HH + i0 + r) * WW + j0 + c4 * 4);
        *(float4*)(ins + r * 68 + c4 * 4) = v;
    }
    __syncthreads();

    // ---- conv0 -> y0T bf16 [pos][c0 (pad 40)], sliding-window float4 ----
    {
        const int c0 = tid & 31;
        const int pg = tid >> 5;      // 0..7; rows 0..5 active
        if (pg < 6) {
            float wreg[9];
            #pragma unroll
            for (int k = 0; k < 9; ++k) wreg[k] = w0[c0 * 9 + k];
            const float bias = b0[c0];
            const float4* rp0 = (const float4*)(ins + (pg    ) * 68);  // 68 = 17 float4
            const float4* rp1 = (const float4*)(ins + (pg + 1) * 68);
            const float4* rp2 = (const float4*)(ins + (pg + 2) * 68);
            unsigned short* yrow = y0T + pg * 66 * 40 + c0;
            float4 a0 = rp0[0], a1 = rp1[0], a2 = rp2[0];
            #pragma unroll 2
            for (int ch = 0; ch < 8; ++ch) {                // cols 8ch..8ch+7
                float4 b0v = rp0[2 * ch + 1], c0v = rp0[2 * ch + 2];
                float4 b1v = rp1[2 * ch + 1], c1v = rp1[2 * ch + 2];
                float4 b2v = rp2[2 * ch + 1], c2v = rp2[2 * ch + 2];
                float r0[12] = {a0.x,a0.y,a0.z,a0.w,b0v.x,b0v.y,b0v.z,b0v.w,c0v.x,c0v.y,c0v.z,c0v.w};
                float r1[12] = {a1.x,a1.y,a1.z,a1.w,b1v.x,b1v.y,b1v.z,b1v.w,c1v.x,c1v.y,c1v.z,c1v.w};
                float r2[12] = {a2.x,a2.y,a2.z,a2.w,b2v.x,b2v.y,b2v.z,b2v.w,c2v.x,c2v.y,c2v.z,c2v.w};
                #pragma unroll
                for (int t = 0; t < 8; ++t) {
                    int col = ch * 8 + t;
                    float a = bias;
                    #pragma unroll
                    for (int kj = 0; kj < 3; ++kj) {
                        a = fmaf(r0[t + kj], wreg[kj],     a);
                        a = fmaf(r1[t + kj], wreg[3 + kj], a);
                        a = fmaf(r2[t + kj], wreg[6 + kj], a);
                    }
                    float v = (j0 + col < 254) ? fmaxf(a, 0.0f) : 0.0f;
                    yrow[col * 40] = f2bf(v);
                }
                a0 = c0v; a1 = c1v; a2 = c2v;               // carry floats 8ch+8..11
            }
            // tail cols 64,65: carried a? = floats 64..67
            {
                float t0[4] = {a0.x, a0.y, a0.z, a0.w};
                float t1[4] = {a1.x, a1.y, a1.z, a1.w};
                float t2[4] = {a2.x, a2.y, a2.z, a2.w};
                #pragma unroll
                for (int t = 0; t < 2; ++t) {
                    int col = 64 + t;
                    float a = bias;
                    #pragma unroll
                    for (int kj = 0; kj < 3; ++kj) {
                        a = fmaf(t0[t + kj], wreg[kj],     a);
                        a = fmaf(t1[t + kj], wreg[3 + kj], a);
                        a = fmaf(t2[t + kj], wreg[6 + kj], a);
                    }
                    float v = (j0 + col < 254) ? fmaxf(a, 0.0f) : 0.0f;
                    yrow[col * 40] = f2bf(v);
                }
            }
        }
    }
    __syncthreads();

    // ---- conv1: 9 tap-GEMMs, K=32(c0). A = w1c (global, L2-hot), B = y0T (LDS) ----
    const int w    = tid >> 6;        // wave id -> output row i0+w
    const int lane = tid & 63;
    const int l15  = lane & 15;
    const int quad = lane >> 4;

    float biasr[4][4];                // [mt][reg]
    #pragma unroll
    for (int mt = 0; mt < 4; ++mt)
        #pragma unroll
        for (int rg = 0; rg < 4; ++rg)
            biasr[mt][rg] = b1[mt * 16 + quad * 4 + rg];

    f32x4 acc[4][4];                  // [mt(ch)][nt(pos)]
    #pragma unroll
    for (int mt = 0; mt < 4; ++mt)
        #pragma unroll
        for (int nt = 0; nt < 4; ++nt)
            acc[mt][nt] = (f32x4){0.f, 0.f, 0.f, 0.f};

    #pragma unroll
    for (int ki = 0; ki < 3; ++ki) {
        #pragma unroll
        for (int kj = 0; kj < 3; ++kj) {
            const int tap = ki * 3 + kj;
            bf16x8 af[4], bfr[4];
            #pragma unroll
            for (int mt = 0; mt < 4; ++mt)   // A[m=c1][k=c0]
                af[mt] = *(const bf16x8*)(w1c + ((tap * 64 + mt * 16 + l15) * 32 + quad * 8));
            #pragma unroll
            for (int nt = 0; nt < 4; ++nt)   // B[k=c0][n=pos]
                bfr[nt] = *(const bf16x8*)(y0T + (((w + ki) * 66 + nt * 16 + l15 + kj) * 40 + quad * 8));
            #pragma unroll
            for (int mt = 0; mt < 4; ++mt)
                #pragma unroll
                for (int nt = 0; nt < 4; ++nt)
                    acc[mt][nt] = __builtin_amdgcn_mfma_f32_16x16x32_bf16(
                        af[mt], bfr[nt], acc[mt][nt], 0, 0, 0);
        }
    }

    // ---- epilogue: relu(x+b1) -> LDS tile [c1][w][j] (rotated), coalesced copy-out ----
    __syncthreads();                  // all waves done reading y0T before aliasing as stg
    #pragma unroll
    for (int mt = 0; mt < 4; ++mt)
        #pragma unroll
        for (int nt = 0; nt < 4; ++nt)
            #pragma unroll
            for (int rg = 0; rg < 4; ++rg) {
                int c1 = mt * 16 + quad * 4 + rg;
                int j  = nt * 16 + l15;
                int jr = (j + (((c1 >> 2) & 3) << 4)) & 63;
                float v = fmaxf(acc[mt][nt][rg] + biasr[mt][rg], 0.0f);
                stg[(c1 * 4 + w) * 64 + jr] = f2bf(v);
            }
    __syncthreads();

    const int limit = (j0 + 64 <= W1N) ? 64 : (W1N - j0);   // 64, or 60 at jt==3
    for (int it2 = 0; it2 < 16; ++it2) {
        int cc = it2 * 256 + tid;     // 0..4095
        int e  = cc * 4;              // element index in [c1][w][j]
        int c1 = e >> 8;
        int w2 = (e >> 6) & 3;
        int jb = e & 63;
        if (jb < limit) {
            int jr = (jb + (((c1 >> 2) & 3) << 4)) & 63;
            *(uint2*)(xbf + (size_t)b * KCNN + (c1 * H1N + i0 + w2) * W1N + j0 + jb) =
                *(const uint2*)(stg + (c1 * 4 + w2) * 64 + jr);
        }
    }
}

// ---------------- K2: LDS-staged split-K MFMA GEMM -> 8-replica atomic gacc ----------
// ROUND 10 CHANGE (pending measurement): the old per-lane fragment loads were 16 disjoint
// 64 B segments per instruction (rows 1.16 MB apart) -> ~64 B-granule HBM traffic at
// ~2.5 TB/s -> k2 ~55us. Now each block cooperatively stages a [32][256] xbf tile +
// [40][256] wr tile (f32->bf16) with fully coalesced wave-wide bursts (512-1024 B
// contiguous per row per wave), then runs the IDENTICAL MFMA fragment pattern out of LDS
// (rows padded to 264 shorts -> 2-way bank aliasing, free). Same f2bf path ->
// bit-identical numerics. 1134 blocks x 2 grid-strided tiles; same reduce/atomic
// epilogue (red aliases staging LDS).
__global__ __launch_bounds__(256) void k2_gemm(
        const unsigned short* __restrict__ xbf, const float* __restrict__ wr,
        float* __restrict__ gacc8) {
    __shared__ __align__(16) char smem[42240];
    unsigned short* lx = (unsigned short*)smem;             // [32][264] = 16896 B
    unsigned short* lw = (unsigned short*)(smem + 16896);   // [48][264] = 25344 B
    float (*red)[32][41] = (float (*)[32][41])smem;         // epilogue alias: 20992 B

    const int tid  = threadIdx.x;
    const int wv   = tid >> 6;
    const int lane = tid & 63;
    const int l15  = lane & 15;
    const int quad = lane >> 4;

    // zero wr-pad rows 40..47 once (f columns 40..47 are discarded by ff<NF below)
    for (int i = tid; i < 264; i += 256) {
        int row = 40 + i / 33, seg = i % 33;
        *(bf16x8*)(lw + row * 264 + seg * 8) = (bf16x8){0,0,0,0,0,0,0,0};
    }

    f32x4 acc[2][3];
    #pragma unroll
    for (int mt = 0; mt < 2; ++mt)
        #pragma unroll
        for (int nt = 0; nt < 3; ++nt)
            acc[mt][nt] = (f32x4){0.f, 0.f, 0.f, 0.f};

    for (int it = 0; it < 2; ++it) {
        const size_t kt = (size_t)(blockIdx.x + it * NBLK2) * KT;
        __syncthreads();              // pad visible (it=0) / prior tile reads done (it=1)

        // stage xbf [32][256] bf16: wave = 2 rows x 512 B contiguous per pass
        for (int i = tid; i < 1024; i += 256) {
            int row = i >> 5, seg = i & 31;
            *(bf16x8*)(lx + row * 264 + seg * 8) =
                *(const bf16x8*)(xbf + (size_t)row * KCNN + kt + seg * 8);
        }
        // stage wr [40][256] f32 -> bf16: wave = 1 row x 1024 B contiguous per pass
        for (int i = tid; i < 2560; i += 256) {
            int row = i >> 6, seg = i & 63;
            float4 v = *(const float4*)(wr + (size_t)row * KCNN + kt + seg * 4);
            ushort4 p = { f2bf(v.x), f2bf(v.y), f2bf(v.z), f2bf(v.w) };
            *(ushort4*)(lw + row * 264 + seg * 4) = p;
        }
        __syncthreads();

        // MFMA: wave wv owns k = wv*64 .. wv*64+63 of this tile
        #pragma unroll
        for (int c = 0; c < 2; ++c) {
            const int lk = wv * 64 + c * 32;
            bf16x8 af[2], bfr[3];
            af[0] = *(const bf16x8*)(lx + (l15     ) * 264 + lk + quad * 8);
            af[1] = *(const bf16x8*)(lx + (16 + l15) * 264 + lk + quad * 8);
            #pragma unroll
            for (int nt = 0; nt < 3; ++nt)
                bfr[nt] = *(const bf16x8*)(lw + (nt * 16 + l15) * 264 + lk + quad * 8);
            #pragma unroll
            for (int nt = 0; nt < 3; ++nt) {
                acc[0][nt] = __builtin_amdgcn_mfma_f32_16x16x32_bf16(af[0], bfr[nt], acc[0][nt], 0, 0, 0);
                acc[1][nt] = __builtin_amdgcn_mfma_f32_16x16x32_bf16(af[1], bfr[nt], acc[1][nt], 0, 0, 0);
            }
        }
    }

    // ---- reduce 4 waves via LDS (aliases staging), then replica atomics ----
    __syncthreads();                  // all MFMA reads done before aliasing as red
    #pragma unroll
    for (int mt = 0; mt < 2; ++mt)
        #pragma unroll
        for (int nt = 0; nt < 3; ++nt)
            #pragma unroll
            for (int rg = 0; rg < 4; ++rg) {
                int bb = mt * 16 + quad * 4 + rg;
                int ff = nt * 16 + l15;
                if (ff < NF) red[wv][bb][ff] = acc[mt][nt][rg];
            }
    __syncthreads();
    float* myg = gacc8 + (size_t)(blockIdx.x & 7) * 1280;
    for (int p = tid; p < 1280; p += 256) {
        int bb = p / 40, ff = p - bb * 40;
        float s = 0.0f;
        #pragma unroll
        for (int w = 0; w < 4; ++w) s += red[w][bb][ff];
        atomicAdd(myg + p, s);
    }
}

// ---------------- K4: gate (from gacc8) + feats -> sin/cos proj -> mods --------
__global__ __launch_bounds__(320) void k4_mods(
        const float* __restrict__ inp, const float* __restrict__ sintab,
        const float* __restrict__ costab, const float* __restrict__ wf,
        const float* __restrict__ bfp, const float* __restrict__ gacc8,
        const float* __restrict__ br, float* __restrict__ out) {
    const int f = blockIdx.x, b = blockIdx.y;
    const int tid = threadIdx.x;
    const int h  = tid >> 3;
    const int wl = tid & 7;

    // gate: 8 replica loads (uniform address -> broadcast), computed redundantly per thread
    float s = 0.0f;
    #pragma unroll
    for (int r = 0; r < 8; ++r) s += gacc8[r * 1280 + b * 40 + f];
    const float g = 1.0f / (1.0f + __expf(-(s + br[f])));
    if (tid == 0)                     // wtd_mean contribution: 1 atomic per block (1280 total)
        atomicAdd(out + 51200, g * (2.0f * (float)(f + 1)) * (1.0f / 1280.0f));

    float wfv[5];
    #pragma unroll
    for (int t = 0; t < 5; ++t) wfv[t] = wf[t];
    const float bias = bfp[0];
    const float* row  = inp + (b * HH + h) * WW;
    const float* srow = sintab + f * 256;
    const float* crow = costab + f * 256;
    float sa = 0.0f, ca = 0.0f;
    for (int m = 0; m < 32; ++m) {
        int w = wl + 8 * m;
        float feat = bias;
        #pragma unroll
        for (int d = -2; d <= 2; ++d) {
            int wc = w + d;
            if (wc >= 0 && wc < WW) feat = fmaf(row[wc], wfv[d + 2], feat);
        }
        sa = fmaf(srow[w], feat, sa);
        ca = fmaf(crow[w], feat, ca);
    }
    #pragma unroll
    for (int off = 4; off >= 1; off >>= 1) {
        sa += __shfl_xor(sa, off, 8);
        ca += __shfl_xor(ca, off, 8);
    }
    if (wl == 0) {
        float mag = sqrtf(sa * sa + ca * ca) * (1.0f / 256.0f);
        out[b * 1600 + f * 40 + h] = mag * g;
    }
}

extern "C" void kernel_launch(void* const* d_in, const int* in_sizes, int n_in,
                              void* d_out, int out_size, void* d_ws, size_t ws_size,
                              hipStream_t stream) {
    const float* inp = (const float*)d_in[0];
    const float* w0  = (const float*)d_in[1];
    const float* b0  = (const float*)d_in[2];
    const float* w1  = (const float*)d_in[3];
    const float* b1  = (const float*)d_in[4];
    const float* wf  = (const float*)d_in[5];
    const float* bf_ = (const float*)d_in[6];
    const float* wr  = (const float*)d_in[7];
    const float* br  = (const float*)d_in[8];
    float* out = (float*)d_out;

    char* ws = (char*)d_ws;
    unsigned short* xbf = (unsigned short*)ws;               // 37,158,912 B
    unsigned short* w1c = (unsigned short*)(ws + 37158912);  // 36,864 B
    float* gacc8  = (float*)(ws + 37195776);                 // 8*1280*4 = 40,960 B
    float* sintab = (float*)(ws + 37236736);                 // 40,960 B
    float* costab = (float*)(ws + 37277696);                 // 40,960 B

    k0_prep<<<72, 256, 0, stream>>>(w1, w1c, gacc8, sintab, costab, out);
    k1_conv<<<dim3(4, 9, 32), 256, 0, stream>>>(inp, w0, b0, w1c, b1, xbf);
    k2_gemm<<<NBLK2, 256, 0, stream>>>(xbf, wr, gacc8);
    k4_mods<<<dim3(40, 32), 320, 0, stream>>>(inp, sintab, costab, wf, bf_, gacc8, br, out);
}

// Round 12
// 232.857 us; speedup vs baseline: 1.0344x; 1.0344x over previous
//
#include <hip/hip_runtime.h>
#include <hip/hip_bf16.h>
#include <math.h>

// Problem constants
#define BB   32
#define HH   40
#define WW   256
#define NF   40          // FREQ
#define H1N  36
#define W1N  252
#define KCNN 580608      // 64*36*252
#define KT2  128         // k2: k per LDS tile
#define NT2  4           // k2: tiles per block
#define NBLK2 1134       // 1134 blocks * 4 tiles * 128 k == KCNN exactly

typedef __attribute__((ext_vector_type(8))) short bf16x8;   // 8 bf16 = 4 VGPRs
typedef __attribute__((ext_vector_type(4))) float f32x4;    // MFMA C/D

static __device__ __forceinline__ unsigned short f2bf(float v) {
    __hip_bfloat16 h = __float2bfloat16(v);
    return *(unsigned short*)&h;
}

static __device__ __forceinline__ bf16x8 packbf(float4 lo, float4 hi) {
    bf16x8 r;
    r[0] = (short)f2bf(lo.x); r[1] = (short)f2bf(lo.y);
    r[2] = (short)f2bf(lo.z); r[3] = (short)f2bf(lo.w);
    r[4] = (short)f2bf(hi.x); r[5] = (short)f2bf(hi.y);
    r[6] = (short)f2bf(hi.z); r[7] = (short)f2bf(hi.w);
    return r;
}

// async global->LDS, 16 B/lane; LDS dest = wave-uniform base + lane*16 (HW-added)
static __device__ __forceinline__ void gll16(const void* g, void* l) {
    __builtin_amdgcn_global_load_lds(
        (const __attribute__((address_space(1))) void*)g,
        (__attribute__((address_space(3))) void*)l, 16, 0, 0);
}

// ---------------- K0: w1 repack f32->bf16; sin/cos table; zero gacc8/mean ----------
__global__ void k0_prep(const float* __restrict__ w1, unsigned short* __restrict__ w1c,
                        float* __restrict__ gacc8, float* __restrict__ sintab,
                        float* __restrict__ costab, float* __restrict__ out) {
    int o = blockIdx.x * 256 + threadIdx.x;   // 72*256 = 18432 = 9*64*32
    int c0  = o & 31;
    int c1  = (o >> 5) & 63;
    int tap = o >> 11;                        // 0..8
    w1c[o] = f2bf(w1[(c1 * 32 + c0) * 9 + tap]);
    if (o < 10240) {                          // 40 f x 256 w phase table + gacc8 zero
        int f = o >> 8, w = o & 255;
        float ph = 6.283185307179586f * (float)(f + 1) * (1.0f / 255.0f) * (float)w;
        sintab[o] = sinf(ph);
        costab[o] = cosf(ph);
        gacc8[o] = 0.0f;                      // 8 replicas x 1280 = 10240 floats
    }
    if (o == 0) out[51200] = 0.0f;
}

// ---------------- K1: fused conv0(relu) + conv1(relu) via bf16 MFMA -> x (bf16) --------
// (byte-identical to round-9/11 measured version)
__global__ __launch_bounds__(256) void k1_conv(
        const float* __restrict__ inp, const float* __restrict__ w0,
        const float* __restrict__ b0, const unsigned short* __restrict__ w1c,
        const float* __restrict__ b1, unsigned short* __restrict__ xbf) {
    __shared__ __align__(16) char smem[33856];
    float* ins = (float*)smem;                              // 544*4  = 2176 B
    unsigned short* y0T = (unsigned short*)(smem + 2176);   // 396*40*2 = 31680 B
    unsigned short* stg = (unsigned short*)smem;            // epilogue reuse: 32768 B

    const int jt = blockIdx.x;        // j0 = 64*jt
    const int it = blockIdx.y;        // i0 = 4*it
    const int b  = blockIdx.z;
    const int i0 = it * 4;
    const int j0 = jt * 64;
    const int tid = threadIdx.x;

    // ---- stage input rows i0..i0+7, cols j0..j0+67 (float4; jt==3 edge zeroed) ----
    if (tid < 136) {
        int r  = tid / 17, c4 = tid - r * 17;
        float4 v = {0.f, 0.f, 0.f, 0.f};
        if (jt < 3 || c4 < 16)        // cols j0+64..67 exceed WW only at jt==3
            v = *(const float4*)(inp + (b * HH + i0 + r) * WW + j0 + c4 * 4);
        *(float4*)(ins + r * 68 + c4 * 4) = v;
    }
    __syncthreads();

    // ---- conv0 -> y0T bf16 [pos][c0 (pad 40)], sliding-window float4 ----
    {
        const int c0 = tid & 31;
        const int pg = tid >> 5;      // 0..7; rows 0..5 active
        if (pg < 6) {
            float wreg[9];
            #pragma unroll
            for (int k = 0; k < 9; ++k) wreg[k] = w0[c0 * 9 + k];
            const float bias = b0[c0];
            const float4* rp0 = (const float4*)(ins + (pg    ) * 68);  // 68 = 17 float4
            const float4* rp1 = (const float4*)(ins + (pg + 1) * 68);
            const float4* rp2 = (const float4*)(ins + (pg + 2) * 68);
            unsigned short* yrow = y0T + pg * 66 * 40 + c0;
            float4 a0 = rp0[0], a1 = rp1[0], a2 = rp2[0];
            #pragma unroll 2
            for (int ch = 0; ch < 8; ++ch) {                // cols 8ch..8ch+7
                float4 b0v = rp0[2 * ch + 1], c0v = rp0[2 * ch + 2];
                float4 b1v = rp1[2 * ch + 1], c1v = rp1[2 * ch + 2];
                float4 b2v = rp2[2 * ch + 1], c2v = rp2[2 * ch + 2];
                float r0[12] = {a0.x,a0.y,a0.z,a0.w,b0v.x,b0v.y,b0v.z,b0v.w,c0v.x,c0v.y,c0v.z,c0v.w};
                float r1[12] = {a1.x,a1.y,a1.z,a1.w,b1v.x,b1v.y,b1v.z,b1v.w,c1v.x,c1v.y,c1v.z,c1v.w};
                float r2[12] = {a2.x,a2.y,a2.z,a2.w,b2v.x,b2v.y,b2v.z,b2v.w,c2v.x,c2v.y,c2v.z,c2v.w};
                #pragma unroll
                for (int t = 0; t < 8; ++t) {
                    int col = ch * 8 + t;
                    float a = bias;
                    #pragma unroll
                    for (int kj = 0; kj < 3; ++kj) {
                        a = fmaf(r0[t + kj], wreg[kj],     a);
                        a = fmaf(r1[t + kj], wreg[3 + kj], a);
                        a = fmaf(r2[t + kj], wreg[6 + kj], a);
                    }
                    float v = (j0 + col < 254) ? fmaxf(a, 0.0f) : 0.0f;
                    yrow[col * 40] = f2bf(v);
                }
                a0 = c0v; a1 = c1v; a2 = c2v;               // carry floats 8ch+8..11
            }
            // tail cols 64,65: carried a? = floats 64..67
            {
                float t0[4] = {a0.x, a0.y, a0.z, a0.w};
                float t1[4] = {a1.x, a1.y, a1.z, a1.w};
                float t2[4] = {a2.x, a2.y, a2.z, a2.w};
                #pragma unroll
                for (int t = 0; t < 2; ++t) {
                    int col = 64 + t;
                    float a = bias;
                    #pragma unroll
                    for (int kj = 0; kj < 3; ++kj) {
                        a = fmaf(t0[t + kj], wreg[kj],     a);
                        a = fmaf(t1[t + kj], wreg[3 + kj], a);
                        a = fmaf(t2[t + kj], wreg[6 + kj], a);
                    }
                    float v = (j0 + col < 254) ? fmaxf(a, 0.0f) : 0.0f;
                    yrow[col * 40] = f2bf(v);
                }
            }
        }
    }
    __syncthreads();

    // ---- conv1: 9 tap-GEMMs, K=32(c0). A = w1c (global, L2-hot), B = y0T (LDS) ----
    const int w    = tid >> 6;        // wave id -> output row i0+w
    const int lane = tid & 63;
    const int l15  = lane & 15;
    const int quad = lane >> 4;

    float biasr[4][4];                // [mt][reg]
    #pragma unroll
    for (int mt = 0; mt < 4; ++mt)
        #pragma unroll
        for (int rg = 0; rg < 4; ++rg)
            biasr[mt][rg] = b1[mt * 16 + quad * 4 + rg];

    f32x4 acc[4][4];                  // [mt(ch)][nt(pos)]
    #pragma unroll
    for (int mt = 0; mt < 4; ++mt)
        #pragma unroll
        for (int nt = 0; nt < 4; ++nt)
            acc[mt][nt] = (f32x4){0.f, 0.f, 0.f, 0.f};

    #pragma unroll
    for (int ki = 0; ki < 3; ++ki) {
        #pragma unroll
        for (int kj = 0; kj < 3; ++kj) {
            const int tap = ki * 3 + kj;
            bf16x8 af[4], bfr[4];
            #pragma unroll
            for (int mt = 0; mt < 4; ++mt)   // A[m=c1][k=c0]
                af[mt] = *(const bf16x8*)(w1c + ((tap * 64 + mt * 16 + l15) * 32 + quad * 8));
            #pragma unroll
            for (int nt = 0; nt < 4; ++nt)   // B[k=c0][n=pos]
                bfr[nt] = *(const bf16x8*)(y0T + (((w + ki) * 66 + nt * 16 + l15 + kj) * 40 + quad * 8));
            #pragma unroll
            for (int mt = 0; mt < 4; ++mt)
                #pragma unroll
                for (int nt = 0; nt < 4; ++nt)
                    acc[mt][nt] = __builtin_amdgcn_mfma_f32_16x16x32_bf16(
                        af[mt], bfr[nt], acc[mt][nt], 0, 0, 0);
        }
    }

    // ---- epilogue: relu(x+b1) -> LDS tile [c1][w][j] (rotated), coalesced copy-out ----
    __syncthreads();                  // all waves done reading y0T before aliasing as stg
    #pragma unroll
    for (int mt = 0; mt < 4; ++mt)
        #pragma unroll
        for (int nt = 0; nt < 4; ++nt)
            #pragma unroll
            for (int rg = 0; rg < 4; ++rg) {
                int c1 = mt * 16 + quad * 4 + rg;
                int j  = nt * 16 + l15;
                int jr = (j + (((c1 >> 2) & 3) << 4)) & 63;
                float v = fmaxf(acc[mt][nt][rg] + biasr[mt][rg], 0.0f);
                stg[(c1 * 4 + w) * 64 + jr] = f2bf(v);
            }
    __syncthreads();

    const int limit = (j0 + 64 <= W1N) ? 64 : (W1N - j0);   // 64, or 60 at jt==3
    for (int it2 = 0; it2 < 16; ++it2) {
        int cc = it2 * 256 + tid;     // 0..4095
        int e  = cc * 4;              // element index in [c1][w][j]
        int c1 = e >> 8;
        int w2 = (e >> 6) & 3;
        int jb = e & 63;
        if (jb < limit) {
            int jr = (jb + (((c1 >> 2) & 3) << 4)) & 63;
            *(uint2*)(xbf + (size_t)b * KCNN + (c1 * H1N + i0 + w2) * W1N + j0 + jb) =
                *(const uint2*)(stg + (c1 * 4 + w2) * 64 + jr);
        }
    }
}

// ---------------- K2: global_load_lds-staged split-K MFMA GEMM -> 8-replica atomics ----
// ROUND 12: round-11 PMC showed k2 latency-bound with ALL pipes idle (Mfma 1.2%, VALU
// 5.7%, HBM 16%, occ 23%): 3 blocks/CU (42.5KB LDS) and reg-round-trip staging gave
// ~1KB in flight per CU vs ~9KB needed. Fix: (a) KT=128 tile -> 32KB LDS -> 5 blocks/CU;
// (b) __builtin_amdgcn_global_load_lds (no VGPR round trip, no load->cvt->write dep
// chain): each wave issues 7x 1KB async loads back-to-back -> ~35KB/CU in flight.
// wr stays f32 in LDS; f2bf conversion moves to fragment-read (same values, same path
// -> bit-identical). Linear LDS (gll constraint); 16-way ds_read conflicts accepted,
// hidden under HBM time (watch SQ_LDS_BANK_CONFLICT).
__global__ __launch_bounds__(256) void k2_gemm(
        const unsigned short* __restrict__ xbf, const float* __restrict__ wr,
        float* __restrict__ gacc8) {
    __shared__ __align__(16) char smem[32768];
    unsigned short* lx = (unsigned short*)smem;          // [32][128] bf16, linear, 8192 B
    float* lwf = (float*)(smem + 8192);                  // [48][128] f32, linear, 24576 B
    float (*red)[32][41] = (float (*)[32][41])smem;      // epilogue alias: 20992 B

    const int tid  = threadIdx.x;
    const int wv   = tid >> 6;
    const int lane = tid & 63;
    const int l15  = lane & 15;
    const int quad = lane >> 4;
    const int gx = lane >> 4, ix = lane & 15;   // lx staging: 4 rows / instr
    const int gw = lane >> 5, iw = lane & 31;   // lwf staging: 2 rows / instr

    // zero lwf pad rows 40..47 (4096 B = 256 threads x 16 B); never re-written
    *(float4*)((char*)lwf + 40 * 512 + tid * 16) = (float4){0.f, 0.f, 0.f, 0.f};

    f32x4 acc[2][3];
    #pragma unroll
    for (int mt = 0; mt < 2; ++mt)
        #pragma unroll
        for (int nt = 0; nt < 3; ++nt)
            acc[mt][nt] = (f32x4){0.f, 0.f, 0.f, 0.f};

    for (int it = 0; it < NT2; ++it) {
        const size_t kt = (size_t)(blockIdx.x * NT2 + it) * KT2;  // contiguous k per block
        __syncthreads();              // pad visible (it=0) / prior tile reads done

        // lx: 8 instrs cover rows 0..31 (4 rows x 1024 B each); wave wv -> j = 2wv..2wv+1
        #pragma unroll
        for (int jj = 0; jj < 2; ++jj) {
            const int j = wv * 2 + jj;
            gll16(xbf + (size_t)(4 * j + gx) * KCNN + kt + ix * 8,
                  (char*)smem + j * 1024);
        }
        // lwf: 20 instrs cover rows 0..39 (2 rows x 1024 B each); wave wv -> j = 5wv..5wv+4
        #pragma unroll
        for (int jj = 0; jj < 5; ++jj) {
            const int j = wv * 5 + jj;
            gll16(wr + (size_t)(2 * j + gw) * KCNN + kt + iw * 4,
                  (char*)smem + 8192 + j * 1024);
        }
        __syncthreads();              // compiler drains vmcnt+lgkmcnt before s_barrier

        // MFMA: wave wv owns k-slice lk = wv*32 of this tile
        const int lk = wv * 32;
        bf16x8 af0 = *(const bf16x8*)(lx + l15 * 128 + lk + quad * 8);
        bf16x8 af1 = *(const bf16x8*)(lx + (16 + l15) * 128 + lk + quad * 8);
        #pragma unroll
        for (int nt = 0; nt < 3; ++nt) {
            const float* bp = lwf + (nt * 16 + l15) * 128 + lk + quad * 8;
            float4 lo = *(const float4*)bp;
            float4 hi = *(const float4*)(bp + 4);
            bf16x8 bfrag = packbf(lo, hi);
            acc[0][nt] = __builtin_amdgcn_mfma_f32_16x16x32_bf16(af0, bfrag, acc[0][nt], 0, 0, 0);
            acc[1][nt] = __builtin_amdgcn_mfma_f32_16x16x32_bf16(af1, bfrag, acc[1][nt], 0, 0, 0);
        }
    }

    // ---- reduce 4 waves via LDS (aliases staging), then replica atomics ----
    __syncthreads();                  // all MFMA reads done before aliasing as red
    #pragma unroll
    for (int mt = 0; mt < 2; ++mt)
        #pragma unroll
        for (int nt = 0; nt < 3; ++nt)
            #pragma unroll
            for (int rg = 0; rg < 4; ++rg) {
                int bb = mt * 16 + quad * 4 + rg;
                int ff = nt * 16 + l15;
                if (ff < NF) red[wv][bb][ff] = acc[mt][nt][rg];
            }
    __syncthreads();
    float* myg = gacc8 + (size_t)(blockIdx.x & 7) * 1280;
    for (int p = tid; p < 1280; p += 256) {
        int bb = p / 40, ff = p - bb * 40;
        float s = 0.0f;
        #pragma unroll
        for (int w = 0; w < 4; ++w) s += red[w][bb][ff];
        atomicAdd(myg + p, s);
    }
}

// ---------------- K4: gate (from gacc8) + feats -> sin/cos proj -> mods --------
__global__ __launch_bounds__(320) void k4_mods(
        const float* __restrict__ inp, const float* __restrict__ sintab,
        const float* __restrict__ costab, const float* __restrict__ wf,
        const float* __restrict__ bfp, const float* __restrict__ gacc8,
        const float* __restrict__ br, float* __restrict__ out) {
    const int f = blockIdx.x, b = blockIdx.y;
    const int tid = threadIdx.x;
    const int h  = tid >> 3;
    const int wl = tid & 7;

    // gate: 8 replica loads (uniform address -> broadcast), computed redundantly per thread
    float s = 0.0f;
    #pragma unroll
    for (int r = 0; r < 8; ++r) s += gacc8[r * 1280 + b * 40 + f];
    const float g = 1.0f / (1.0f + __expf(-(s + br[f])));
    if (tid == 0)                     // wtd_mean contribution: 1 atomic per block (1280 total)
        atomicAdd(out + 51200, g * (2.0f * (float)(f + 1)) * (1.0f / 1280.0f));

    float wfv[5];
    #pragma unroll
    for (int t = 0; t < 5; ++t) wfv[t] = wf[t];
    const float bias = bfp[0];
    const float* row  = inp + (b * HH + h) * WW;
    const float* srow = sintab + f * 256;
    const float* crow = costab + f * 256;
    float sa = 0.0f, ca = 0.0f;
    for (int m = 0; m < 32; ++m) {
        int w = wl + 8 * m;
        float feat = bias;
        #pragma unroll
        for (int d = -2; d <= 2; ++d) {
            int wc = w + d;
            if (wc >= 0 && wc < WW) feat = fmaf(row[wc], wfv[d + 2], feat);
        }
        sa = fmaf(srow[w], feat, sa);
        ca = fmaf(crow[w], feat, ca);
    }
    #pragma unroll
    for (int off = 4; off >= 1; off >>= 1) {
        sa += __shfl_xor(sa, off, 8);
        ca += __shfl_xor(ca, off, 8);
    }
    if (wl == 0) {
        float mag = sqrtf(sa * sa + ca * ca) * (1.0f / 256.0f);
        out[b * 1600 + f * 40 + h] = mag * g;
    }
}

extern "C" void kernel_launch(void* const* d_in, const int* in_sizes, int n_in,
                              void* d_out, int out_size, void* d_ws, size_t ws_size,
                              hipStream_t stream) {
    const float* inp = (const float*)d_in[0];
    const float* w0  = (const float*)d_in[1];
    const float* b0  = (const float*)d_in[2];
    const float* w1  = (const float*)d_in[3];
    const float* b1  = (const float*)d_in[4];
    const float* wf  = (const float*)d_in[5];
    const float* bf_ = (const float*)d_in[6];
    const float* wr  = (const float*)d_in[7];
    const float* br  = (const float*)d_in[8];
    float* out = (float*)d_out;

    char* ws = (char*)d_ws;
    unsigned short* xbf = (unsigned short*)ws;               // 37,158,912 B
    unsigned short* w1c = (unsigned short*)(ws + 37158912);  // 36,864 B
    float* gacc8  = (float*)(ws + 37195776);                 // 8*1280*4 = 40,960 B
    float* sintab = (float*)(ws + 37236736);                 // 40,960 B
    float* costab = (float*)(ws + 37277696);                 // 40,960 B

    k0_prep<<<72, 256, 0, stream>>>(w1, w1c, gacc8, sintab, costab, out);
    k1_conv<<<dim3(4, 9, 32), 256, 0, stream>>>(inp, w0, b0, w1c, b1, xbf);
    k2_gemm<<<NBLK2, 256, 0, stream>>>(xbf, wr, gacc8);
    k4_mods<<<dim3(40, 32), 320, 0, stream>>>(inp, sintab, costab, wf, bf_, gacc8, br, out);
}

// Round 13
// 229.316 us; speedup vs baseline: 1.0504x; 1.0154x over previous
//
#include <hip/hip_runtime.h>
#include <hip/hip_bf16.h>
#include <math.h>

// Problem constants
#define BB   32
#define HH   40
#define WW   256
#define NF   40          // FREQ
#define H1N  36
#define W1N  252
#define KCNN 580608      // 64*36*252
#define KT2  128         // k2: k per LDS tile
#define NT2  4           // k2: tiles per block
#define NBLK2 1134       // 1134 blocks * 4 tiles * 128 k == KCNN exactly

typedef __attribute__((ext_vector_type(8))) short bf16x8;   // 8 bf16 = 4 VGPRs
typedef __attribute__((ext_vector_type(4))) float f32x4;    // MFMA C/D

static __device__ __forceinline__ unsigned short f2bf(float v) {
    __hip_bfloat16 h = __float2bfloat16(v);
    return *(unsigned short*)&h;
}

static __device__ __forceinline__ bf16x8 packbf(float4 lo, float4 hi) {
    bf16x8 r;
    r[0] = (short)f2bf(lo.x); r[1] = (short)f2bf(lo.y);
    r[2] = (short)f2bf(lo.z); r[3] = (short)f2bf(lo.w);
    r[4] = (short)f2bf(hi.x); r[5] = (short)f2bf(hi.y);
    r[6] = (short)f2bf(hi.z); r[7] = (short)f2bf(hi.w);
    return r;
}

// async global->LDS, 16 B/lane; LDS dest = wave-uniform base + lane*16 (HW-added)
static __device__ __forceinline__ void gll16(const void* g, void* l) {
    __builtin_amdgcn_global_load_lds(
        (const __attribute__((address_space(1))) void*)g,
        (__attribute__((address_space(3))) void*)l, 16, 0, 0);
}

// ---------------- K0: w1 repack f32->bf16; sin/cos table; zero gacc8/mean ----------
__global__ void k0_prep(const float* __restrict__ w1, unsigned short* __restrict__ w1c,
                        float* __restrict__ gacc8, float* __restrict__ sintab,
                        float* __restrict__ costab, float* __restrict__ out) {
    int o = blockIdx.x * 256 + threadIdx.x;   // 72*256 = 18432 = 9*64*32
    int c0  = o & 31;
    int c1  = (o >> 5) & 63;
    int tap = o >> 11;                        // 0..8
    w1c[o] = f2bf(w1[(c1 * 32 + c0) * 9 + tap]);
    if (o < 10240) {                          // 40 f x 256 w phase table + gacc8 zero
        int f = o >> 8, w = o & 255;
        float ph = 6.283185307179586f * (float)(f + 1) * (1.0f / 255.0f) * (float)w;
        sintab[o] = sinf(ph);
        costab[o] = cosf(ph);
        gacc8[o] = 0.0f;                      // 8 replicas x 1280 = 10240 floats
    }
    if (o == 0) out[51200] = 0.0f;
}

// ---------------- K1: fused conv0(relu) + conv1(relu) via bf16 MFMA -> x (bf16) --------
// (byte-identical to round-9/11/12 measured version)
__global__ __launch_bounds__(256) void k1_conv(
        const float* __restrict__ inp, const float* __restrict__ w0,
        const float* __restrict__ b0, const unsigned short* __restrict__ w1c,
        const float* __restrict__ b1, unsigned short* __restrict__ xbf) {
    __shared__ __align__(16) char smem[33856];
    float* ins = (float*)smem;                              // 544*4  = 2176 B
    unsigned short* y0T = (unsigned short*)(smem + 2176);   // 396*40*2 = 31680 B
    unsigned short* stg = (unsigned short*)smem;            // epilogue reuse: 32768 B

    const int jt = blockIdx.x;        // j0 = 64*jt
    const int it = blockIdx.y;        // i0 = 4*it
    const int b  = blockIdx.z;
    const int i0 = it * 4;
    const int j0 = jt * 64;
    const int tid = threadIdx.x;

    // ---- stage input rows i0..i0+7, cols j0..j0+67 (float4; jt==3 edge zeroed) ----
    if (tid < 136) {
        int r  = tid / 17, c4 = tid - r * 17;
        float4 v = {0.f, 0.f, 0.f, 0.f};
        if (jt < 3 || c4 < 16)        // cols j0+64..67 exceed WW only at jt==3
            v = *(const float4*)(inp + (b * HH + i0 + r) * WW + j0 + c4 * 4);
        *(float4*)(ins + r * 68 + c4 * 4) = v;
    }
    __syncthreads();

    // ---- conv0 -> y0T bf16 [pos][c0 (pad 40)], sliding-window float4 ----
    {
        const int c0 = tid & 31;
        const int pg = tid >> 5;      // 0..7; rows 0..5 active
        if (pg < 6) {
            float wreg[9];
            #pragma unroll
            for (int k = 0; k < 9; ++k) wreg[k] = w0[c0 * 9 + k];
            const float bias = b0[c0];
            const float4* rp0 = (const float4*)(ins + (pg    ) * 68);  // 68 = 17 float4
            const float4* rp1 = (const float4*)(ins + (pg + 1) * 68);
            const float4* rp2 = (const float4*)(ins + (pg + 2) * 68);
            unsigned short* yrow = y0T + pg * 66 * 40 + c0;
            float4 a0 = rp0[0], a1 = rp1[0], a2 = rp2[0];
            #pragma unroll 2
            for (int ch = 0; ch < 8; ++ch) {                // cols 8ch..8ch+7
                float4 b0v = rp0[2 * ch + 1], c0v = rp0[2 * ch + 2];
                float4 b1v = rp1[2 * ch + 1], c1v = rp1[2 * ch + 2];
                float4 b2v = rp2[2 * ch + 1], c2v = rp2[2 * ch + 2];
                float r0[12] = {a0.x,a0.y,a0.z,a0.w,b0v.x,b0v.y,b0v.z,b0v.w,c0v.x,c0v.y,c0v.z,c0v.w};
                float r1[12] = {a1.x,a1.y,a1.z,a1.w,b1v.x,b1v.y,b1v.z,b1v.w,c1v.x,c1v.y,c1v.z,c1v.w};
                float r2[12] = {a2.x,a2.y,a2.z,a2.w,b2v.x,b2v.y,b2v.z,b2v.w,c2v.x,c2v.y,c2v.z,c2v.w};
                #pragma unroll
                for (int t = 0; t < 8; ++t) {
                    int col = ch * 8 + t;
                    float a = bias;
                    #pragma unroll
                    for (int kj = 0; kj < 3; ++kj) {
                        a = fmaf(r0[t + kj], wreg[kj],     a);
                        a = fmaf(r1[t + kj], wreg[3 + kj], a);
                        a = fmaf(r2[t + kj], wreg[6 + kj], a);
                    }
                    float v = (j0 + col < 254) ? fmaxf(a, 0.0f) : 0.0f;
                    yrow[col * 40] = f2bf(v);
                }
                a0 = c0v; a1 = c1v; a2 = c2v;               // carry floats 8ch+8..11
            }
            // tail cols 64,65: carried a? = floats 64..67
            {
                float t0[4] = {a0.x, a0.y, a0.z, a0.w};
                float t1[4] = {a1.x, a1.y, a1.z, a1.w};
                float t2[4] = {a2.x, a2.y, a2.z, a2.w};
                #pragma unroll
                for (int t = 0; t < 2; ++t) {
                    int col = 64 + t;
                    float a = bias;
                    #pragma unroll
                    for (int kj = 0; kj < 3; ++kj) {
                        a = fmaf(t0[t + kj], wreg[kj],     a);
                        a = fmaf(t1[t + kj], wreg[3 + kj], a);
                        a = fmaf(t2[t + kj], wreg[6 + kj], a);
                    }
                    float v = (j0 + col < 254) ? fmaxf(a, 0.0f) : 0.0f;
                    yrow[col * 40] = f2bf(v);
                }
            }
        }
    }
    __syncthreads();

    // ---- conv1: 9 tap-GEMMs, K=32(c0). A = w1c (global, L2-hot), B = y0T (LDS) ----
    const int w    = tid >> 6;        // wave id -> output row i0+w
    const int lane = tid & 63;
    const int l15  = lane & 15;
    const int quad = lane >> 4;

    float biasr[4][4];                // [mt][reg]
    #pragma unroll
    for (int mt = 0; mt < 4; ++mt)
        #pragma unroll
        for (int rg = 0; rg < 4; ++rg)
            biasr[mt][rg] = b1[mt * 16 + quad * 4 + rg];

    f32x4 acc[4][4];                  // [mt(ch)][nt(pos)]
    #pragma unroll
    for (int mt = 0; mt < 4; ++mt)
        #pragma unroll
        for (int nt = 0; nt < 4; ++nt)
            acc[mt][nt] = (f32x4){0.f, 0.f, 0.f, 0.f};

    #pragma unroll
    for (int ki = 0; ki < 3; ++ki) {
        #pragma unroll
        for (int kj = 0; kj < 3; ++kj) {
            const int tap = ki * 3 + kj;
            bf16x8 af[4], bfr[4];
            #pragma unroll
            for (int mt = 0; mt < 4; ++mt)   // A[m=c1][k=c0]
                af[mt] = *(const bf16x8*)(w1c + ((tap * 64 + mt * 16 + l15) * 32 + quad * 8));
            #pragma unroll
            for (int nt = 0; nt < 4; ++nt)   // B[k=c0][n=pos]
                bfr[nt] = *(const bf16x8*)(y0T + (((w + ki) * 66 + nt * 16 + l15 + kj) * 40 + quad * 8));
            #pragma unroll
            for (int mt = 0; mt < 4; ++mt)
                #pragma unroll
                for (int nt = 0; nt < 4; ++nt)
                    acc[mt][nt] = __builtin_amdgcn_mfma_f32_16x16x32_bf16(
                        af[mt], bfr[nt], acc[mt][nt], 0, 0, 0);
        }
    }

    // ---- epilogue: relu(x+b1) -> LDS tile [c1][w][j] (rotated), coalesced copy-out ----
    __syncthreads();                  // all waves done reading y0T before aliasing as stg
    #pragma unroll
    for (int mt = 0; mt < 4; ++mt)
        #pragma unroll
        for (int nt = 0; nt < 4; ++nt)
            #pragma unroll
            for (int rg = 0; rg < 4; ++rg) {
                int c1 = mt * 16 + quad * 4 + rg;
                int j  = nt * 16 + l15;
                int jr = (j + (((c1 >> 2) & 3) << 4)) & 63;
                float v = fmaxf(acc[mt][nt][rg] + biasr[mt][rg], 0.0f);
                stg[(c1 * 4 + w) * 64 + jr] = f2bf(v);
            }
    __syncthreads();

    const int limit = (j0 + 64 <= W1N) ? 64 : (W1N - j0);   // 64, or 60 at jt==3
    for (int it2 = 0; it2 < 16; ++it2) {
        int cc = it2 * 256 + tid;     // 0..4095
        int e  = cc * 4;              // element index in [c1][w][j]
        int c1 = e >> 8;
        int w2 = (e >> 6) & 3;
        int jb = e & 63;
        if (jb < limit) {
            int jr = (jb + (((c1 >> 2) & 3) << 4)) & 63;
            *(uint2*)(xbf + (size_t)b * KCNN + (c1 * H1N + i0 + w2) * W1N + j0 + jb) =
                *(const uint2*)(stg + (c1 * 4 + w2) * 64 + jr);
        }
    }
}

// ---------------- K2: gll-staged split-K MFMA GEMM, XOR-swizzled LDS -> atomics ----
// ROUND 13: round-12's linear LDS rows (256/512 B stride) made every MFMA fragment
// read a 16-way bank collision (all l15 lanes same bank quartet; G4 row-major case).
// Fix per rule #21 (gll writes linearly -> swizzle BOTH other sides): per-lane GLOBAL
// source address pre-permuted with col ^= (row&7)<<4 (16B-granule involution inside
// each row; same cache lines, coalescing preserved), and fragment reads apply the
// same XOR. Values/conversion path unchanged -> bit-identical numerics.
__global__ __launch_bounds__(256) void k2_gemm(
        const unsigned short* __restrict__ xbf, const float* __restrict__ wr,
        float* __restrict__ gacc8) {
    __shared__ __align__(16) char smem[32768];
    char* lx  = smem;                 // [32 rows][256 B] bf16, col-swizzled
    char* lwf = smem + 8192;          // [48 rows][512 B] f32,  col-swizzled
    float (*red)[32][41] = (float (*)[32][41])smem;      // epilogue alias: 20992 B

    const int tid  = threadIdx.x;
    const int wv   = tid >> 6;
    const int lane = tid & 63;
    const int l15  = lane & 15;
    const int quad = lane >> 4;
    const int gx = lane >> 4, ix = lane & 15;   // lx staging: 4 rows / instr
    const int gw = lane >> 5, iw = lane & 31;   // lwf staging: 2 rows / instr

    // zero lwf pad rows 40..47 (4096 B); XOR-reads stay within each row -> still zero
    *(float4*)(lwf + 40 * 512 + tid * 16) = (float4){0.f, 0.f, 0.f, 0.f};

    f32x4 acc[2][3];
    #pragma unroll
    for (int mt = 0; mt < 2; ++mt)
        #pragma unroll
        for (int nt = 0; nt < 3; ++nt)
            acc[mt][nt] = (f32x4){0.f, 0.f, 0.f, 0.f};

    for (int it = 0; it < NT2; ++it) {
        const size_t kt = (size_t)(blockIdx.x * NT2 + it) * KT2;  // contiguous k per block
        __syncthreads();              // pad visible (it=0) / prior tile reads done

        // lx: 8 instrs, 4 rows x 256 B each; source col pre-swizzled (bf16 idx = bytes/2)
        #pragma unroll
        for (int jj = 0; jj < 2; ++jj) {
            const int j = wv * 2 + jj;
            const int row = 4 * j + gx;
            const int csrc = (ix * 16) ^ ((row & 7) << 4);        // bytes within row
            gll16(xbf + (size_t)row * KCNN + kt + (csrc >> 1),
                  lx + j * 1024);
        }
        // lwf: 20 instrs, 2 rows x 512 B each; source col pre-swizzled (f32 idx = bytes/4)
        #pragma unroll
        for (int jj = 0; jj < 5; ++jj) {
            const int j = wv * 5 + jj;
            const int row = 2 * j + gw;
            const int csrc = (iw * 16) ^ ((row & 7) << 4);        // bytes within row
            gll16(wr + (size_t)row * KCNN + kt + (csrc >> 2),
                  lwf + j * 1024);
        }
        __syncthreads();              // compiler drains vmcnt+lgkmcnt before s_barrier

        // MFMA: wave wv owns k-slice lk = wv*32 (bf16) of this tile; reads XOR-swizzled
        const int m8 = (l15 & 7) << 4;                 // row-derived XOR mask (bytes)
        const int cx = wv * 64 + quad * 16;            // lx byte col
        bf16x8 af0 = *(const bf16x8*)(lx + l15 * 256 + (cx ^ m8));
        bf16x8 af1 = *(const bf16x8*)(lx + (16 + l15) * 256 + (cx ^ m8));   // (16+l15)&7 == l15&7
        const int cw = wv * 128 + quad * 32;           // lwf byte col (lo half)
        #pragma unroll
        for (int nt = 0; nt < 3; ++nt) {
            const char* rowp = lwf + (nt * 16 + l15) * 512;       // (nt*16+l15)&7 == l15&7
            float4 lo = *(const float4*)(rowp + ((cw     ) ^ m8));
            float4 hi = *(const float4*)(rowp + ((cw + 16) ^ m8));
            bf16x8 bfrag = packbf(lo, hi);
            acc[0][nt] = __builtin_amdgcn_mfma_f32_16x16x32_bf16(af0, bfrag, acc[0][nt], 0, 0, 0);
            acc[1][nt] = __builtin_amdgcn_mfma_f32_16x16x32_bf16(af1, bfrag, acc[1][nt], 0, 0, 0);
        }
    }

    // ---- reduce 4 waves via LDS (aliases staging), then replica atomics ----
    __syncthreads();                  // all MFMA reads done before aliasing as red
    #pragma unroll
    for (int mt = 0; mt < 2; ++mt)
        #pragma unroll
        for (int nt = 0; nt < 3; ++nt)
            #pragma unroll
            for (int rg = 0; rg < 4; ++rg) {
                int bb = mt * 16 + quad * 4 + rg;
                int ff = nt * 16 + l15;
                if (ff < NF) red[wv][bb][ff] = acc[mt][nt][rg];
            }
    __syncthreads();
    float* myg = gacc8 + (size_t)(blockIdx.x & 7) * 1280;
    for (int p = tid; p < 1280; p += 256) {
        int bb = p / 40, ff = p - bb * 40;
        float s = 0.0f;
        #pragma unroll
        for (int w = 0; w < 4; ++w) s += red[w][bb][ff];
        atomicAdd(myg + p, s);
    }
}

// ---------------- K4: gate (from gacc8) + feats -> sin/cos proj -> mods --------
__global__ __launch_bounds__(320) void k4_mods(
        const float* __restrict__ inp, const float* __restrict__ sintab,
        const float* __restrict__ costab, const float* __restrict__ wf,
        const float* __restrict__ bfp, const float* __restrict__ gacc8,
        const float* __restrict__ br, float* __restrict__ out) {
    const int f = blockIdx.x, b = blockIdx.y;
    const int tid = threadIdx.x;
    const int h  = tid >> 3;
    const int wl = tid & 7;

    // gate: 8 replica loads (uniform address -> broadcast), computed redundantly per thread
    float s = 0.0f;
    #pragma unroll
    for (int r = 0; r < 8; ++r) s += gacc8[r * 1280 + b * 40 + f];
    const float g = 1.0f / (1.0f + __expf(-(s + br[f])));
    if (tid == 0)                     // wtd_mean contribution: 1 atomic per block (1280 total)
        atomicAdd(out + 51200, g * (2.0f * (float)(f + 1)) * (1.0f / 1280.0f));

    float wfv[5];
    #pragma unroll
    for (int t = 0; t < 5; ++t) wfv[t] = wf[t];
    const float bias = bfp[0];
    const float* row  = inp + (b * HH + h) * WW;
    const float* srow = sintab + f * 256;
    const float* crow = costab + f * 256;
    float sa = 0.0f, ca = 0.0f;
    for (int m = 0; m < 32; ++m) {
        int w = wl + 8 * m;
        float feat = bias;
        #pragma unroll
        for (int d = -2; d <= 2; ++d) {
            int wc = w + d;
            if (wc >= 0 && wc < WW) feat = fmaf(row[wc], wfv[d + 2], feat);
        }
        sa = fmaf(srow[w], feat, sa);
        ca = fmaf(crow[w], feat, ca);
    }
    #pragma unroll
    for (int off = 4; off >= 1; off >>= 1) {
        sa += __shfl_xor(sa, off, 8);
        ca += __shfl_xor(ca, off, 8);
    }
    if (wl == 0) {
        float mag = sqrtf(sa * sa + ca * ca) * (1.0f / 256.0f);
        out[b * 1600 + f * 40 + h] = mag * g;
    }
}

extern "C" void kernel_launch(void* const* d_in, const int* in_sizes, int n_in,
                              void* d_out, int out_size, void* d_ws, size_t ws_size,
                              hipStream_t stream) {
    const float* inp = (const float*)d_in[0];
    const float* w0  = (const float*)d_in[1];
    const float* b0  = (const float*)d_in[2];
    const float* w1  = (const float*)d_in[3];
    const float* b1  = (const float*)d_in[4];
    const float* wf  = (const float*)d_in[5];
    const float* bf_ = (const float*)d_in[6];
    const float* wr  = (const float*)d_in[7];
    const float* br  = (const float*)d_in[8];
    float* out = (float*)d_out;

    char* ws = (char*)d_ws;
    unsigned short* xbf = (unsigned short*)ws;               // 37,158,912 B
    unsigned short* w1c = (unsigned short*)(ws + 37158912);  // 36,864 B
    float* gacc8  = (float*)(ws + 37195776);                 // 8*1280*4 = 40,960 B
    float* sintab = (float*)(ws + 37236736);                 // 40,960 B
    float* costab = (float*)(ws + 37277696);                 // 40,960 B

    k0_prep<<<72, 256, 0, stream>>>(w1, w1c, gacc8, sintab, costab, out);
    k1_conv<<<dim3(4, 9, 32), 256, 0, stream>>>(inp, w0, b0, w1c, b1, xbf);
    k2_gemm<<<NBLK2, 256, 0, stream>>>(xbf, wr, gacc8);
    k4_mods<<<dim3(40, 32), 320, 0, stream>>>(inp, sintab, costab, wf, bf_, gacc8, br, out);
}

// Round 14
// 216.055 us; speedup vs baseline: 1.1148x; 1.0614x over previous
//
#include <hip/hip_runtime.h>
#include <hip/hip_bf16.h>
#include <math.h>

// Problem constants
#define BB   32
#define HH   40
#define WW   256
#define NF   40          // FREQ
#define H1N  36
#define W1N  252
#define KCNN 580608      // 64*36*252
#define KT2  128         // k2: k per LDS tile
#define NT2  4           // k2: tiles per block
#define NBLK2 1134       // 1134 blocks * 4 tiles * 128 k == KCNN exactly

typedef __attribute__((ext_vector_type(8))) short bf16x8;   // 8 bf16 = 4 VGPRs
typedef __attribute__((ext_vector_type(4))) float f32x4;    // MFMA C/D

static __device__ __forceinline__ unsigned short f2bf(float v) {
    __hip_bfloat16 h = __float2bfloat16(v);
    return *(unsigned short*)&h;
}

static __device__ __forceinline__ bf16x8 packbf(float4 lo, float4 hi) {
    bf16x8 r;
    r[0] = (short)f2bf(lo.x); r[1] = (short)f2bf(lo.y);
    r[2] = (short)f2bf(lo.z); r[3] = (short)f2bf(lo.w);
    r[4] = (short)f2bf(hi.x); r[5] = (short)f2bf(hi.y);
    r[6] = (short)f2bf(hi.z); r[7] = (short)f2bf(hi.w);
    return r;
}

// async global->LDS, 16 B/lane; LDS dest = wave-uniform base + lane*16 (HW-added)
static __device__ __forceinline__ void gll16(const void* g, void* l) {
    __builtin_amdgcn_global_load_lds(
        (const __attribute__((address_space(1))) void*)g,
        (__attribute__((address_space(3))) void*)l, 16, 0, 0);
}

// ---------------- K0: w1 repack f32->bf16; sin/cos table; zero gacc8/mean ----------
__global__ void k0_prep(const float* __restrict__ w1, unsigned short* __restrict__ w1c,
                        float* __restrict__ gacc8, float* __restrict__ sintab,
                        float* __restrict__ costab, float* __restrict__ out) {
    int o = blockIdx.x * 256 + threadIdx.x;   // 72*256 = 18432 = 9*64*32
    int c0  = o & 31;
    int c1  = (o >> 5) & 63;
    int tap = o >> 11;                        // 0..8
    w1c[o] = f2bf(w1[(c1 * 32 + c0) * 9 + tap]);
    if (o < 10240) {                          // 40 f x 256 w phase table + gacc8 zero
        int f = o >> 8, w = o & 255;
        float ph = 6.283185307179586f * (float)(f + 1) * (1.0f / 255.0f) * (float)w;
        sintab[o] = sinf(ph);
        costab[o] = cosf(ph);
        gacc8[o] = 0.0f;                      // 8 replicas x 1280 = 10240 floats
    }
    if (o == 0) out[51200] = 0.0f;
}

// ---------------- K1: fused conv0(relu) + conv1(relu) via bf16 MFMA -> x (bf16) --------
// (byte-identical to round-9/11/12/13 measured version)
__global__ __launch_bounds__(256) void k1_conv(
        const float* __restrict__ inp, const float* __restrict__ w0,
        const float* __restrict__ b0, const unsigned short* __restrict__ w1c,
        const float* __restrict__ b1, unsigned short* __restrict__ xbf) {
    __shared__ __align__(16) char smem[33856];
    float* ins = (float*)smem;                              // 544*4  = 2176 B
    unsigned short* y0T = (unsigned short*)(smem + 2176);   // 396*40*2 = 31680 B
    unsigned short* stg = (unsigned short*)smem;            // epilogue reuse: 32768 B

    const int jt = blockIdx.x;        // j0 = 64*jt
    const int it = blockIdx.y;        // i0 = 4*it
    const int b  = blockIdx.z;
    const int i0 = it * 4;
    const int j0 = jt * 64;
    const int tid = threadIdx.x;

    // ---- stage input rows i0..i0+7, cols j0..j0+67 (float4; jt==3 edge zeroed) ----
    if (tid < 136) {
        int r  = tid / 17, c4 = tid - r * 17;
        float4 v = {0.f, 0.f, 0.f, 0.f};
        if (jt < 3 || c4 < 16)        // cols j0+64..67 exceed WW only at jt==3
            v = *(const float4*)(inp + (b * HH + i0 + r) * WW + j0 + c4 * 4);
        *(float4*)(ins + r * 68 + c4 * 4) = v;
    }
    __syncthreads();

    // ---- conv0 -> y0T bf16 [pos][c0 (pad 40)], sliding-window float4 ----
    {
        const int c0 = tid & 31;
        const int pg = tid >> 5;      // 0..7; rows 0..5 active
        if (pg < 6) {
            float wreg[9];
            #pragma unroll
            for (int k = 0; k < 9; ++k) wreg[k] = w0[c0 * 9 + k];
            const float bias = b0[c0];
            const float4* rp0 = (const float4*)(ins + (pg    ) * 68);  // 68 = 17 float4
            const float4* rp1 = (const float4*)(ins + (pg + 1) * 68);
            const float4* rp2 = (const float4*)(ins + (pg + 2) * 68);
            unsigned short* yrow = y0T + pg * 66 * 40 + c0;
            float4 a0 = rp0[0], a1 = rp1[0], a2 = rp2[0];
            #pragma unroll 2
            for (int ch = 0; ch < 8; ++ch) {                // cols 8ch..8ch+7
                float4 b0v = rp0[2 * ch + 1], c0v = rp0[2 * ch + 2];
                float4 b1v = rp1[2 * ch + 1], c1v = rp1[2 * ch + 2];
                float4 b2v = rp2[2 * ch + 1], c2v = rp2[2 * ch + 2];
                float r0[12] = {a0.x,a0.y,a0.z,a0.w,b0v.x,b0v.y,b0v.z,b0v.w,c0v.x,c0v.y,c0v.z,c0v.w};
                float r1[12] = {a1.x,a1.y,a1.z,a1.w,b1v.x,b1v.y,b1v.z,b1v.w,c1v.x,c1v.y,c1v.z,c1v.w};
                float r2[12] = {a2.x,a2.y,a2.z,a2.w,b2v.x,b2v.y,b2v.z,b2v.w,c2v.x,c2v.y,c2v.z,c2v.w};
                #pragma unroll
                for (int t = 0; t < 8; ++t) {
                    int col = ch * 8 + t;
                    float a = bias;
                    #pragma unroll
                    for (int kj = 0; kj < 3; ++kj) {
                        a = fmaf(r0[t + kj], wreg[kj],     a);
                        a = fmaf(r1[t + kj], wreg[3 + kj], a);
                        a = fmaf(r2[t + kj], wreg[6 + kj], a);
                    }
                    float v = (j0 + col < 254) ? fmaxf(a, 0.0f) : 0.0f;
                    yrow[col * 40] = f2bf(v);
                }
                a0 = c0v; a1 = c1v; a2 = c2v;               // carry floats 8ch+8..11
            }
            // tail cols 64,65: carried a? = floats 64..67
            {
                float t0[4] = {a0.x, a0.y, a0.z, a0.w};
                float t1[4] = {a1.x, a1.y, a1.z, a1.w};
                float t2[4] = {a2.x, a2.y, a2.z, a2.w};
                #pragma unroll
                for (int t = 0; t < 2; ++t) {
                    int col = 64 + t;
                    float a = bias;
                    #pragma unroll
                    for (int kj = 0; kj < 3; ++kj) {
                        a = fmaf(t0[t + kj], wreg[kj],     a);
                        a = fmaf(t1[t + kj], wreg[3 + kj], a);
                        a = fmaf(t2[t + kj], wreg[6 + kj], a);
                    }
                    float v = (j0 + col < 254) ? fmaxf(a, 0.0f) : 0.0f;
                    yrow[col * 40] = f2bf(v);
                }
            }
        }
    }
    __syncthreads();

    // ---- conv1: 9 tap-GEMMs, K=32(c0). A = w1c (global, L2-hot), B = y0T (LDS) ----
    const int w    = tid >> 6;        // wave id -> output row i0+w
    const int lane = tid & 63;
    const int l15  = lane & 15;
    const int quad = lane >> 4;

    float biasr[4][4];                // [mt][reg]
    #pragma unroll
    for (int mt = 0; mt < 4; ++mt)
        #pragma unroll
        for (int rg = 0; rg < 4; ++rg)
            biasr[mt][rg] = b1[mt * 16 + quad * 4 + rg];

    f32x4 acc[4][4];                  // [mt(ch)][nt(pos)]
    #pragma unroll
    for (int mt = 0; mt < 4; ++mt)
        #pragma unroll
        for (int nt = 0; nt < 4; ++nt)
            acc[mt][nt] = (f32x4){0.f, 0.f, 0.f, 0.f};

    #pragma unroll
    for (int ki = 0; ki < 3; ++ki) {
        #pragma unroll
        for (int kj = 0; kj < 3; ++kj) {
            const int tap = ki * 3 + kj;
            bf16x8 af[4], bfr[4];
            #pragma unroll
            for (int mt = 0; mt < 4; ++mt)   // A[m=c1][k=c0]
                af[mt] = *(const bf16x8*)(w1c + ((tap * 64 + mt * 16 + l15) * 32 + quad * 8));
            #pragma unroll
            for (int nt = 0; nt < 4; ++nt)   // B[k=c0][n=pos]
                bfr[nt] = *(const bf16x8*)(y0T + (((w + ki) * 66 + nt * 16 + l15 + kj) * 40 + quad * 8));
            #pragma unroll
            for (int mt = 0; mt < 4; ++mt)
                #pragma unroll
                for (int nt = 0; nt < 4; ++nt)
                    acc[mt][nt] = __builtin_amdgcn_mfma_f32_16x16x32_bf16(
                        af[mt], bfr[nt], acc[mt][nt], 0, 0, 0);
        }
    }

    // ---- epilogue: relu(x+b1) -> LDS tile [c1][w][j] (rotated), coalesced copy-out ----
    __syncthreads();                  // all waves done reading y0T before aliasing as stg
    #pragma unroll
    for (int mt = 0; mt < 4; ++mt)
        #pragma unroll
        for (int nt = 0; nt < 4; ++nt)
            #pragma unroll
            for (int rg = 0; rg < 4; ++rg) {
                int c1 = mt * 16 + quad * 4 + rg;
                int j  = nt * 16 + l15;
                int jr = (j + (((c1 >> 2) & 3) << 4)) & 63;
                float v = fmaxf(acc[mt][nt][rg] + biasr[mt][rg], 0.0f);
                stg[(c1 * 4 + w) * 64 + jr] = f2bf(v);
            }
    __syncthreads();

    const int limit = (j0 + 64 <= W1N) ? 64 : (W1N - j0);   // 64, or 60 at jt==3
    for (int it2 = 0; it2 < 16; ++it2) {
        int cc = it2 * 256 + tid;     // 0..4095
        int e  = cc * 4;              // element index in [c1][w][j]
        int c1 = e >> 8;
        int w2 = (e >> 6) & 3;
        int jb = e & 63;
        if (jb < limit) {
            int jr = (jb + (((c1 >> 2) & 3) << 4)) & 63;
            *(uint2*)(xbf + (size_t)b * KCNN + (c1 * H1N + i0 + w2) * W1N + j0 + jb) =
                *(const uint2*)(stg + (c1 * 4 + w2) * 64 + jr);
        }
    }
}

// ---------------- K2: gll-staged split-K MFMA GEMM, XOR-swizzled LDS -> atomics ----
// (byte-identical to round-13 measured version)
__global__ __launch_bounds__(256) void k2_gemm(
        const unsigned short* __restrict__ xbf, const float* __restrict__ wr,
        float* __restrict__ gacc8) {
    __shared__ __align__(16) char smem[32768];
    char* lx  = smem;                 // [32 rows][256 B] bf16, col-swizzled
    char* lwf = smem + 8192;          // [48 rows][512 B] f32,  col-swizzled
    float (*red)[32][41] = (float (*)[32][41])smem;      // epilogue alias: 20992 B

    const int tid  = threadIdx.x;
    const int wv   = tid >> 6;
    const int lane = tid & 63;
    const int l15  = lane & 15;
    const int quad = lane >> 4;
    const int gx = lane >> 4, ix = lane & 15;   // lx staging: 4 rows / instr
    const int gw = lane >> 5, iw = lane & 31;   // lwf staging: 2 rows / instr

    // zero lwf pad rows 40..47 (4096 B); XOR-reads stay within each row -> still zero
    *(float4*)(lwf + 40 * 512 + tid * 16) = (float4){0.f, 0.f, 0.f, 0.f};

    f32x4 acc[2][3];
    #pragma unroll
    for (int mt = 0; mt < 2; ++mt)
        #pragma unroll
        for (int nt = 0; nt < 3; ++nt)
            acc[mt][nt] = (f32x4){0.f, 0.f, 0.f, 0.f};

    for (int it = 0; it < NT2; ++it) {
        const size_t kt = (size_t)(blockIdx.x * NT2 + it) * KT2;  // contiguous k per block
        __syncthreads();              // pad visible (it=0) / prior tile reads done

        // lx: 8 instrs, 4 rows x 256 B each; source col pre-swizzled (bf16 idx = bytes/2)
        #pragma unroll
        for (int jj = 0; jj < 2; ++jj) {
            const int j = wv * 2 + jj;
            const int row = 4 * j + gx;
            const int csrc = (ix * 16) ^ ((row & 7) << 4);        // bytes within row
            gll16(xbf + (size_t)row * KCNN + kt + (csrc >> 1),
                  lx + j * 1024);
        }
        // lwf: 20 instrs, 2 rows x 512 B each; source col pre-swizzled (f32 idx = bytes/4)
        #pragma unroll
        for (int jj = 0; jj < 5; ++jj) {
            const int j = wv * 5 + jj;
            const int row = 2 * j + gw;
            const int csrc = (iw * 16) ^ ((row & 7) << 4);        // bytes within row
            gll16(wr + (size_t)row * KCNN + kt + (csrc >> 2),
                  lwf + j * 1024);
        }
        __syncthreads();              // compiler drains vmcnt+lgkmcnt before s_barrier

        // MFMA: wave wv owns k-slice lk = wv*32 (bf16) of this tile; reads XOR-swizzled
        const int m8 = (l15 & 7) << 4;                 // row-derived XOR mask (bytes)
        const int cx = wv * 64 + quad * 16;            // lx byte col
        bf16x8 af0 = *(const bf16x8*)(lx + l15 * 256 + (cx ^ m8));
        bf16x8 af1 = *(const bf16x8*)(lx + (16 + l15) * 256 + (cx ^ m8));   // (16+l15)&7 == l15&7
        const int cw = wv * 128 + quad * 32;           // lwf byte col (lo half)
        #pragma unroll
        for (int nt = 0; nt < 3; ++nt) {
            const char* rowp = lwf + (nt * 16 + l15) * 512;       // (nt*16+l15)&7 == l15&7
            float4 lo = *(const float4*)(rowp + ((cw     ) ^ m8));
            float4 hi = *(const float4*)(rowp + ((cw + 16) ^ m8));
            bf16x8 bfrag = packbf(lo, hi);
            acc[0][nt] = __builtin_amdgcn_mfma_f32_16x16x32_bf16(af0, bfrag, acc[0][nt], 0, 0, 0);
            acc[1][nt] = __builtin_amdgcn_mfma_f32_16x16x32_bf16(af1, bfrag, acc[1][nt], 0, 0, 0);
        }
    }

    // ---- reduce 4 waves via LDS (aliases staging), then replica atomics ----
    __syncthreads();                  // all MFMA reads done before aliasing as red
    #pragma unroll
    for (int mt = 0; mt < 2; ++mt)
        #pragma unroll
        for (int nt = 0; nt < 3; ++nt)
            #pragma unroll
            for (int rg = 0; rg < 4; ++rg) {
                int bb = mt * 16 + quad * 4 + rg;
                int ff = nt * 16 + l15;
                if (ff < NF) red[wv][bb][ff] = acc[mt][nt][rg];
            }
    __syncthreads();
    float* myg = gacc8 + (size_t)(blockIdx.x & 7) * 1280;
    for (int p = tid; p < 1280; p += 256) {
        int bb = p / 40, ff = p - bb * 40;
        float s = 0.0f;
        #pragma unroll
        for (int w = 0; w < 4; ++w) s += red[w][bb][ff];
        atomicAdd(myg + p, s);
    }
}

// ---------------- K4: gate (from gacc8) + feats -> sin/cos proj -> mods --------
// ROUND 14: the round-7 fold made 1280 blocks atomicAdd the SAME address (out+51200) --
// same-line float atomics serialize at one L2 bank (~25-38us chain; matches the
// 219->229.6 regression at round 7). Fix: block (f=0,b=0) alone computes the complete
// wtd_mean (1280 gates recomputed from L2-hot gacc8, wave+LDS reduce, ONE plain store,
// zero atomics); other blocks skip. Mods path unchanged.
__global__ __launch_bounds__(320) void k4_mods(
        const float* __restrict__ inp, const float* __restrict__ sintab,
        const float* __restrict__ costab, const float* __restrict__ wf,
        const float* __restrict__ bfp, const float* __restrict__ gacc8,
        const float* __restrict__ br, float* __restrict__ out) {
    const int f = blockIdx.x, b = blockIdx.y;
    const int tid = threadIdx.x;
    const int h  = tid >> 3;
    const int wl = tid & 7;

    // gate for this block's (b,f): 8 replica loads (uniform address -> broadcast)
    float s = 0.0f;
    #pragma unroll
    for (int r = 0; r < 8; ++r) s += gacc8[r * 1280 + b * 40 + f];
    const float g = 1.0f / (1.0f + __expf(-(s + br[f])));

    // block (0,0) alone computes the full weighted mean -> one plain store, no atomics
    if (f == 0 && b == 0) {
        __shared__ float wsum[5];     // 320 threads = 5 waves
        float c = 0.0f;
        for (int p = tid; p < 1280; p += 320) {   // exactly 4 p per thread
            float s2 = 0.0f;
            #pragma unroll
            for (int r = 0; r < 8; ++r) s2 += gacc8[r * 1280 + p];
            int ff = p % 40;
            float gg = 1.0f / (1.0f + __expf(-(s2 + br[ff])));
            c += gg * (2.0f * (float)(ff + 1)) * (1.0f / 1280.0f);
        }
        #pragma unroll
        for (int off = 32; off >= 1; off >>= 1) c += __shfl_down(c, off, 64);
        if ((tid & 63) == 0) wsum[tid >> 6] = c;
        __syncthreads();
        if (tid == 0) out[51200] = wsum[0] + wsum[1] + wsum[2] + wsum[3] + wsum[4];
    }

    float wfv[5];
    #pragma unroll
    for (int t = 0; t < 5; ++t) wfv[t] = wf[t];
    const float bias = bfp[0];
    const float* row  = inp + (b * HH + h) * WW;
    const float* srow = sintab + f * 256;
    const float* crow = costab + f * 256;
    float sa = 0.0f, ca = 0.0f;
    for (int m = 0; m < 32; ++m) {
        int w = wl + 8 * m;
        float feat = bias;
        #pragma unroll
        for (int d = -2; d <= 2; ++d) {
            int wc = w + d;
            if (wc >= 0 && wc < WW) feat = fmaf(row[wc], wfv[d + 2], feat);
        }
        sa = fmaf(srow[w], feat, sa);
        ca = fmaf(crow[w], feat, ca);
    }
    #pragma unroll
    for (int off = 4; off >= 1; off >>= 1) {
        sa += __shfl_xor(sa, off, 8);
        ca += __shfl_xor(ca, off, 8);
    }
    if (wl == 0) {
        float mag = sqrtf(sa * sa + ca * ca) * (1.0f / 256.0f);
        out[b * 1600 + f * 40 + h] = mag * g;
    }
}

extern "C" void kernel_launch(void* const* d_in, const int* in_sizes, int n_in,
                              void* d_out, int out_size, void* d_ws, size_t ws_size,
                              hipStream_t stream) {
    const float* inp = (const float*)d_in[0];
    const float* w0  = (const float*)d_in[1];
    const float* b0  = (const float*)d_in[2];
    const float* w1  = (const float*)d_in[3];
    const float* b1  = (const float*)d_in[4];
    const float* wf  = (const float*)d_in[5];
    const float* bf_ = (const float*)d_in[6];
    const float* wr  = (const float*)d_in[7];
    const float* br  = (const float*)d_in[8];
    float* out = (float*)d_out;

    char* ws = (char*)d_ws;
    unsigned short* xbf = (unsigned short*)ws;               // 37,158,912 B
    unsigned short* w1c = (unsigned short*)(ws + 37158912);  // 36,864 B
    float* gacc8  = (float*)(ws + 37195776);                 // 8*1280*4 = 40,960 B
    float* sintab = (float*)(ws + 37236736);                 // 40,960 B
    float* costab = (float*)(ws + 37277696);                 // 40,960 B

    k0_prep<<<72, 256, 0, stream>>>(w1, w1c, gacc8, sintab, costab, out);
    k1_conv<<<dim3(4, 9, 32), 256, 0, stream>>>(inp, w0, b0, w1c, b1, xbf);
    k2_gemm<<<NBLK2, 256, 0, stream>>>(xbf, wr, gacc8);
    k4_mods<<<dim3(40, 32), 320, 0, stream>>>(inp, sintab, costab, wf, bf_, gacc8, br, out);
}

// Round 17
// 211.518 us; speedup vs baseline: 1.1387x; 1.0214x over previous
//
#include <hip/hip_runtime.h>
#include <hip/hip_bf16.h>
#include <math.h>

// Problem constants
#define BB   32
#define HH   40
#define WW   256
#define NF   40          // FREQ
#define H1N  36
#define W1N  252
#define KCNN 580608      // 64*36*252
#define KT2  128         // k2: k per LDS tile
#define NT2  4           // k2: tiles per block
#define NBLK2 1134       // 1134 blocks * 4 tiles * 128 k == KCNN exactly

typedef __attribute__((ext_vector_type(8))) short bf16x8;   // 8 bf16 = 4 VGPRs
typedef __attribute__((ext_vector_type(4))) float f32x4;    // MFMA C/D

static __device__ __forceinline__ unsigned short f2bf(float v) {
    __hip_bfloat16 h = __float2bfloat16(v);
    return *(unsigned short*)&h;
}

static __device__ __forceinline__ bf16x8 packbf(float4 lo, float4 hi) {
    bf16x8 r;
    r[0] = (short)f2bf(lo.x); r[1] = (short)f2bf(lo.y);
    r[2] = (short)f2bf(lo.z); r[3] = (short)f2bf(lo.w);
    r[4] = (short)f2bf(hi.x); r[5] = (short)f2bf(hi.y);
    r[6] = (short)f2bf(hi.z); r[7] = (short)f2bf(hi.w);
    return r;
}

// async global->LDS, 16 B/lane; LDS dest = wave-uniform base + lane*16 (HW-added)
static __device__ __forceinline__ void gll16(const void* g, void* l) {
    __builtin_amdgcn_global_load_lds(
        (const __attribute__((address_space(1))) void*)g,
        (__attribute__((address_space(3))) void*)l, 16, 0, 0);
}

// ---------------- K0: w1 repack f32->bf16; sin/cos table; zero gacc8/mean ----------
__global__ void k0_prep(const float* __restrict__ w1, unsigned short* __restrict__ w1c,
                        float* __restrict__ gacc8, float* __restrict__ sintab,
                        float* __restrict__ costab, float* __restrict__ out) {
    int o = blockIdx.x * 256 + threadIdx.x;   // 72*256 = 18432 = 9*64*32
    int c0  = o & 31;
    int c1  = (o >> 5) & 63;
    int tap = o >> 11;                        // 0..8
    w1c[o] = f2bf(w1[(c1 * 32 + c0) * 9 + tap]);
    if (o < 10240) {                          // 40 f x 256 w phase table + gacc8 zero
        int f = o >> 8, w = o & 255;
        float ph = 6.283185307179586f * (float)(f + 1) * (1.0f / 255.0f) * (float)w;
        sintab[o] = sinf(ph);
        costab[o] = cosf(ph);
        gacc8[o] = 0.0f;                      // 8 replicas x 1280 = 10240 floats
    }
    if (o == 0) out[51200] = 0.0f;
}

// ---------------- K1: fused conv0(relu) + conv1(relu) via bf16 MFMA -> x (bf16) --------
// (byte-identical to round-14 measured version)
__global__ __launch_bounds__(256) void k1_conv(
        const float* __restrict__ inp, const float* __restrict__ w0,
        const float* __restrict__ b0, const unsigned short* __restrict__ w1c,
        const float* __restrict__ b1, unsigned short* __restrict__ xbf) {
    __shared__ __align__(16) char smem[33856];
    float* ins = (float*)smem;                              // 544*4  = 2176 B
    unsigned short* y0T = (unsigned short*)(smem + 2176);   // 396*40*2 = 31680 B
    unsigned short* stg = (unsigned short*)smem;            // epilogue reuse: 32768 B

    const int jt = blockIdx.x;        // j0 = 64*jt
    const int it = blockIdx.y;        // i0 = 4*it
    const int b  = blockIdx.z;
    const int i0 = it * 4;
    const int j0 = jt * 64;
    const int tid = threadIdx.x;

    // ---- stage input rows i0..i0+7, cols j0..j0+67 (float4; jt==3 edge zeroed) ----
    if (tid < 136) {
        int r  = tid / 17, c4 = tid - r * 17;
        float4 v = {0.f, 0.f, 0.f, 0.f};
        if (jt < 3 || c4 < 16)        // cols j0+64..67 exceed WW only at jt==3
            v = *(const float4*)(inp + (b * HH + i0 + r) * WW + j0 + c4 * 4);
        *(float4*)(ins + r * 68 + c4 * 4) = v;
    }
    __syncthreads();

    // ---- conv0 -> y0T bf16 [pos][c0 (pad 40)], sliding-window float4 ----
    {
        const int c0 = tid & 31;
        const int pg = tid >> 5;      // 0..7; rows 0..5 active
        if (pg < 6) {
            float wreg[9];
            #pragma unroll
            for (int k = 0; k < 9; ++k) wreg[k] = w0[c0 * 9 + k];
            const float bias = b0[c0];
            const float4* rp0 = (const float4*)(ins + (pg    ) * 68);  // 68 = 17 float4
            const float4* rp1 = (const float4*)(ins + (pg + 1) * 68);
            const float4* rp2 = (const float4*)(ins + (pg + 2) * 68);
            unsigned short* yrow = y0T + pg * 66 * 40 + c0;
            float4 a0 = rp0[0], a1 = rp1[0], a2 = rp2[0];
            #pragma unroll 2
            for (int ch = 0; ch < 8; ++ch) {                // cols 8ch..8ch+7
                float4 b0v = rp0[2 * ch + 1], c0v = rp0[2 * ch + 2];
                float4 b1v = rp1[2 * ch + 1], c1v = rp1[2 * ch + 2];
                float4 b2v = rp2[2 * ch + 1], c2v = rp2[2 * ch + 2];
                float r0[12] = {a0.x,a0.y,a0.z,a0.w,b0v.x,b0v.y,b0v.z,b0v.w,c0v.x,c0v.y,c0v.z,c0v.w};
                float r1[12] = {a1.x,a1.y,a1.z,a1.w,b1v.x,b1v.y,b1v.z,b1v.w,c1v.x,c1v.y,c1v.z,c1v.w};
                float r2[12] = {a2.x,a2.y,a2.z,a2.w,b2v.x,b2v.y,b2v.z,b2v.w,c2v.x,c2v.y,c2v.z,c2v.w};
                #pragma unroll
                for (int t = 0; t < 8; ++t) {
                    int col = ch * 8 + t;
                    float a = bias;
                    #pragma unroll
                    for (int kj = 0; kj < 3; ++kj) {
                        a = fmaf(r0[t + kj], wreg[kj],     a);
                        a = fmaf(r1[t + kj], wreg[3 + kj], a);
                        a = fmaf(r2[t + kj], wreg[6 + kj], a);
                    }
                    float v = (j0 + col < 254) ? fmaxf(a, 0.0f) : 0.0f;
                    yrow[col * 40] = f2bf(v);
                }
                a0 = c0v; a1 = c1v; a2 = c2v;               // carry floats 8ch+8..11
            }
            // tail cols 64,65: carried a? = floats 64..67
            {
                float t0[4] = {a0.x, a0.y, a0.z, a0.w};
                float t1[4] = {a1.x, a1.y, a1.z, a1.w};
                float t2[4] = {a2.x, a2.y, a2.z, a2.w};
                #pragma unroll
                for (int t = 0; t < 2; ++t) {
                    int col = 64 + t;
                    float a = bias;
                    #pragma unroll
                    for (int kj = 0; kj < 3; ++kj) {
                        a = fmaf(t0[t + kj], wreg[kj],     a);
                        a = fmaf(t1[t + kj], wreg[3 + kj], a);
                        a = fmaf(t2[t + kj], wreg[6 + kj], a);
                    }
                    float v = (j0 + col < 254) ? fmaxf(a, 0.0f) : 0.0f;
                    yrow[col * 40] = f2bf(v);
                }
            }
        }
    }
    __syncthreads();

    // ---- conv1: 9 tap-GEMMs, K=32(c0). A = w1c (global, L2-hot), B = y0T (LDS) ----
    const int w    = tid >> 6;        // wave id -> output row i0+w
    const int lane = tid & 63;
    const int l15  = lane & 15;
    const int quad = lane >> 4;

    float biasr[4][4];                // [mt][reg]
    #pragma unroll
    for (int mt = 0; mt < 4; ++mt)
        #pragma unroll
        for (int rg = 0; rg < 4; ++rg)
            biasr[mt][rg] = b1[mt * 16 + quad * 4 + rg];

    f32x4 acc[4][4];                  // [mt(ch)][nt(pos)]
    #pragma unroll
    for (int mt = 0; mt < 4; ++mt)
        #pragma unroll
        for (int nt = 0; nt < 4; ++nt)
            acc[mt][nt] = (f32x4){0.f, 0.f, 0.f, 0.f};

    #pragma unroll
    for (int ki = 0; ki < 3; ++ki) {
        #pragma unroll
        for (int kj = 0; kj < 3; ++kj) {
            const int tap = ki * 3 + kj;
            bf16x8 af[4], bfr[4];
            #pragma unroll
            for (int mt = 0; mt < 4; ++mt)   // A[m=c1][k=c0]
                af[mt] = *(const bf16x8*)(w1c + ((tap * 64 + mt * 16 + l15) * 32 + quad * 8));
            #pragma unroll
            for (int nt = 0; nt < 4; ++nt)   // B[k=c0][n=pos]
                bfr[nt] = *(const bf16x8*)(y0T + (((w + ki) * 66 + nt * 16 + l15 + kj) * 40 + quad * 8));
            #pragma unroll
            for (int mt = 0; mt < 4; ++mt)
                #pragma unroll
                for (int nt = 0; nt < 4; ++nt)
                    acc[mt][nt] = __builtin_amdgcn_mfma_f32_16x16x32_bf16(
                        af[mt], bfr[nt], acc[mt][nt], 0, 0, 0);
        }
    }

    // ---- epilogue: relu(x+b1) -> LDS tile [c1][w][j] (rotated), coalesced copy-out ----
    __syncthreads();                  // all waves done reading y0T before aliasing as stg
    #pragma unroll
    for (int mt = 0; mt < 4; ++mt)
        #pragma unroll
        for (int nt = 0; nt < 4; ++nt)
            #pragma unroll
            for (int rg = 0; rg < 4; ++rg) {
                int c1 = mt * 16 + quad * 4 + rg;
                int j  = nt * 16 + l15;
                int jr = (j + (((c1 >> 2) & 3) << 4)) & 63;
                float v = fmaxf(acc[mt][nt][rg] + biasr[mt][rg], 0.0f);
                stg[(c1 * 4 + w) * 64 + jr] = f2bf(v);
            }
    __syncthreads();

    const int limit = (j0 + 64 <= W1N) ? 64 : (W1N - j0);   // 64, or 60 at jt==3
    for (int it2 = 0; it2 < 16; ++it2) {
        int cc = it2 * 256 + tid;     // 0..4095
        int e  = cc * 4;              // element index in [c1][w][j]
        int c1 = e >> 8;
        int w2 = (e >> 6) & 3;
        int jb = e & 63;
        if (jb < limit) {
            int jr = (jb + (((c1 >> 2) & 3) << 4)) & 63;
            *(uint2*)(xbf + (size_t)b * KCNN + (c1 * H1N + i0 + w2) * W1N + j0 + jb) =
                *(const uint2*)(stg + (c1 * 4 + w2) * 64 + jr);
        }
    }
}

// ---------------- K2: gll-staged split-K MFMA GEMM, occupancy-tuned -> atomics ----
// ROUND 15 (pending measurement): round-11 PMC showed VGPR=68; occupancy quantization
// (waves halve at vgpr {64,128,256}) rounds 68 up to the 128-class -> only 16 waves/CU.
// Changes, all serving "double resident waves": (a) __launch_bounds__(256,8) forces
// <=64 VGPR; (b) lwf staged as bf16 via registers (same f2bf values -> bit-identical;
// XOR-swizzled ds_write_b128; linear coalesced global reads) -> LDS 32768->18432;
// (c) red stride 41->40 -> 20480 B alloc -> 8 blocks/CU by LDS. B-fragment LDS
// bytes halved; packbf leaves the MFMA loop. lx path (gll + pre-swizzled source)
// unchanged from round 13.
__global__ __launch_bounds__(256, 8) void k2_gemm(
        const unsigned short* __restrict__ xbf, const float* __restrict__ wr,
        float* __restrict__ gacc8) {
    __shared__ __align__(16) char smem[20480];
    char* lx  = smem;                 // [32 rows][256 B] bf16, col-swizzled (gll)
    char* lwf = smem + 8192;          // [48 rows][256 B] bf16, col-swizzled (reg-staged)
    float (*red)[32][40] = (float (*)[32][40])smem;      // epilogue alias: 20480 B

    const int tid  = threadIdx.x;
    const int wv   = tid >> 6;
    const int lane = tid & 63;
    const int l15  = lane & 15;
    const int quad = lane >> 4;
    const int gx = lane >> 4, ix = lane & 15;   // lx staging: 4 rows / instr

    // zero lwf pad rows 40..47 (8 rows x 256 B = 2048 B = 256 threads x 8 B)
    *(uint2*)(lwf + 40 * 256 + tid * 8) = (uint2){0u, 0u};

    f32x4 acc[2][3];
    #pragma unroll
    for (int mt = 0; mt < 2; ++mt)
        #pragma unroll
        for (int nt = 0; nt < 3; ++nt)
            acc[mt][nt] = (f32x4){0.f, 0.f, 0.f, 0.f};

    for (int it = 0; it < NT2; ++it) {
        const size_t kt = (size_t)(blockIdx.x * NT2 + it) * KT2;  // contiguous k per block
        __syncthreads();              // pad visible (it=0) / prior tile reads done

        // lx: 8 instrs, 4 rows x 256 B each; source col pre-swizzled (bf16 idx = bytes/2)
        #pragma unroll
        for (int jj = 0; jj < 2; ++jj) {
            const int j = wv * 2 + jj;
            const int row = 4 * j + gx;
            const int csrc = (ix * 16) ^ ((row & 7) << 4);        // bytes within row
            gll16(xbf + (size_t)row * KCNN + kt + (csrc >> 1),
                  lx + j * 1024);
        }
        // lwf: reg-staged f32->bf16. 640 16B-chunks; chunk i: row=i>>4, c16=i&15.
        // Global reads linear (wave = 4 rows x 512 B contiguous); ds_write XOR-swizzled.
        for (int i = tid; i < 640; i += 256) {
            const int row = i >> 4, c16 = i & 15;
            const float* gp = wr + (size_t)row * KCNN + kt + c16 * 8;
            float4 lo = *(const float4*)gp;
            float4 hi = *(const float4*)(gp + 4);
            *(bf16x8*)(lwf + row * 256 + ((c16 * 16) ^ ((row & 7) << 4))) = packbf(lo, hi);
        }
        __syncthreads();              // drains vmcnt+lgkmcnt before s_barrier

        // MFMA: wave wv owns k-slice of this tile; reads XOR-swizzled
        const int m8 = (l15 & 7) << 4;                 // row-derived XOR mask (bytes)
        const int cx = wv * 64 + quad * 16;            // byte col (both lx and lwf)
        bf16x8 af0 = *(const bf16x8*)(lx + l15 * 256 + (cx ^ m8));
        bf16x8 af1 = *(const bf16x8*)(lx + (16 + l15) * 256 + (cx ^ m8));   // (16+l15)&7 == l15&7
        #pragma unroll
        for (int nt = 0; nt < 3; ++nt) {
            bf16x8 bfrag = *(const bf16x8*)(lwf + (nt * 16 + l15) * 256 + (cx ^ m8));
            acc[0][nt] = __builtin_amdgcn_mfma_f32_16x16x32_bf16(af0, bfrag, acc[0][nt], 0, 0, 0);
            acc[1][nt] = __builtin_amdgcn_mfma_f32_16x16x32_bf16(af1, bfrag, acc[1][nt], 0, 0, 0);
        }
    }

    // ---- reduce 4 waves via LDS (aliases staging), then replica atomics ----
    __syncthreads();                  // all MFMA reads done before aliasing as red
    #pragma unroll
    for (int mt = 0; mt < 2; ++mt)
        #pragma unroll
        for (int nt = 0; nt < 3; ++nt)
            #pragma unroll
            for (int rg = 0; rg < 4; ++rg) {
                int bb = mt * 16 + quad * 4 + rg;
                int ff = nt * 16 + l15;
                if (ff < NF) red[wv][bb][ff] = acc[mt][nt][rg];
            }
    __syncthreads();
    float* myg = gacc8 + (size_t)(blockIdx.x & 7) * 1280;
    for (int p = tid; p < 1280; p += 256) {
        int bb = p / 40, ff = p - bb * 40;
        float s = 0.0f;
        #pragma unroll
        for (int w = 0; w < 4; ++w) s += red[w][bb][ff];
        atomicAdd(myg + p, s);
    }
}

// ---------------- K4: gate (from gacc8) + feats -> sin/cos proj -> mods --------
// (byte-identical to round-14 measured version: block (0,0) computes wtd_mean alone,
// one plain store, zero atomics)
__global__ __launch_bounds__(320) void k4_mods(
        const float* __restrict__ inp, const float* __restrict__ sintab,
        const float* __restrict__ costab, const float* __restrict__ wf,
        const float* __restrict__ bfp, const float* __restrict__ gacc8,
        const float* __restrict__ br, float* __restrict__ out) {
    const int f = blockIdx.x, b = blockIdx.y;
    const int tid = threadIdx.x;
    const int h  = tid >> 3;
    const int wl = tid & 7;

    // gate for this block's (b,f): 8 replica loads (uniform address -> broadcast)
    float s = 0.0f;
    #pragma unroll
    for (int r = 0; r < 8; ++r) s += gacc8[r * 1280 + b * 40 + f];
    const float g = 1.0f / (1.0f + __expf(-(s + br[f])));

    // block (0,0) alone computes the full weighted mean -> one plain store, no atomics
    if (f == 0 && b == 0) {
        __shared__ float wsum[5];     // 320 threads = 5 waves
        float c = 0.0f;
        for (int p = tid; p < 1280; p += 320) {   // exactly 4 p per thread
            float s2 = 0.0f;
            #pragma unroll
            for (int r = 0; r < 8; ++r) s2 += gacc8[r * 1280 + p];
            int ff = p % 40;
            float gg = 1.0f / (1.0f + __expf(-(s2 + br[ff])));
            c += gg * (2.0f * (float)(ff + 1)) * (1.0f / 1280.0f);
        }
        #pragma unroll
        for (int off = 32; off >= 1; off >>= 1) c += __shfl_down(c, off, 64);
        if ((tid & 63) == 0) wsum[tid >> 6] = c;
        __syncthreads();
        if (tid == 0) out[51200] = wsum[0] + wsum[1] + wsum[2] + wsum[3] + wsum[4];
    }

    float wfv[5];
    #pragma unroll
    for (int t = 0; t < 5; ++t) wfv[t] = wf[t];
    const float bias = bfp[0];
    const float* row  = inp + (b * HH + h) * WW;
    const float* srow = sintab + f * 256;
    const float* crow = costab + f * 256;
    float sa = 0.0f, ca = 0.0f;
    for (int m = 0; m < 32; ++m) {
        int w = wl + 8 * m;
        float feat = bias;
        #pragma unroll
        for (int d = -2; d <= 2; ++d) {
            int wc = w + d;
            if (wc >= 0 && wc < WW) feat = fmaf(row[wc], wfv[d + 2], feat);
        }
        sa = fmaf(srow[w], feat, sa);
        ca = fmaf(crow[w], feat, ca);
    }
    #pragma unroll
    for (int off = 4; off >= 1; off >>= 1) {
        sa += __shfl_xor(sa, off, 8);
        ca += __shfl_xor(ca, off, 8);
    }
    if (wl == 0) {
        float mag = sqrtf(sa * sa + ca * ca) * (1.0f / 256.0f);
        out[b * 1600 + f * 40 + h] = mag * g;
    }
}

extern "C" void kernel_launch(void* const* d_in, const int* in_sizes, int n_in,
                              void* d_out, int out_size, void* d_ws, size_t ws_size,
                              hipStream_t stream) {
    const float* inp = (const float*)d_in[0];
    const float* w0  = (const float*)d_in[1];
    const float* b0  = (const float*)d_in[2];
    const float* w1  = (const float*)d_in[3];
    const float* b1  = (const float*)d_in[4];
    const float* wf  = (const float*)d_in[5];
    const float* bf_ = (const float*)d_in[6];
    const float* wr  = (const float*)d_in[7];
    const float* br  = (const float*)d_in[8];
    float* out = (float*)d_out;

    char* ws = (char*)d_ws;
    unsigned short* xbf = (unsigned short*)ws;               // 37,158,912 B
    unsigned short* w1c = (unsigned short*)(ws + 37158912);  // 36,864 B
    float* gacc8  = (float*)(ws + 37195776);                 // 8*1280*4 = 40,960 B
    float* sintab = (float*)(ws + 37236736);                 // 40,960 B
    float* costab = (float*)(ws + 37277696);                 // 40,960 B

    k0_prep<<<72, 256, 0, stream>>>(w1, w1c, gacc8, sintab, costab, out);
    k1_conv<<<dim3(4, 9, 32), 256, 0, stream>>>(inp, w0, b0, w1c, b1, xbf);
    k2_gemm<<<NBLK2, 256, 0, stream>>>(xbf, wr, gacc8);
    k4_mods<<<dim3(40, 32), 320, 0, stream>>>(inp, sintab, costab, wf, bf_, gacc8, br, out);
}